// Round 1
// baseline (1645.995 us; speedup 1.0000x reference)
//
#include <hip/hip_runtime.h>

#define EPS_LN 1e-5f

// ---------------- CSR build (dst-indexed) ----------------
__global__ void k_deg(const int* __restrict__ ei, int* __restrict__ deg, int E, int N){
  int e = blockIdx.x * 256 + threadIdx.x;
  if (e >= E + N) return;
  int dst = (e < E) ? ei[E + e] : (e - E);   // self loops appended
  atomicAdd(&deg[dst], 1);
}

__global__ __launch_bounds__(1024) void k_scan(const int* __restrict__ deg, int* __restrict__ row_ptr,
                                               int* __restrict__ cursor, int n){
  __shared__ int lds[1024];
  __shared__ int carry;
  if (threadIdx.x == 0){ carry = 0; row_ptr[0] = 0; }
  __syncthreads();
  for (int base = 0; base < n; base += 1024){
    int i = base + (int)threadIdx.x;
    int v = (i < n) ? deg[i] : 0;
    lds[threadIdx.x] = v;
    __syncthreads();
    for (int off = 1; off < 1024; off <<= 1){
      int t = (threadIdx.x >= (unsigned)off) ? lds[threadIdx.x - off] : 0;
      __syncthreads();
      lds[threadIdx.x] += t;
      __syncthreads();
    }
    int inc = lds[threadIdx.x] + carry;
    if (i < n){ row_ptr[i + 1] = inc; cursor[i] = inc - v; }
    __syncthreads();
    if (threadIdx.x == 1023) carry = inc;
    __syncthreads();
  }
}

__global__ void k_scatter(const int* __restrict__ ei, int* __restrict__ cursor,
                          int* __restrict__ csr_src, int E, int N){
  int e = blockIdx.x * 256 + threadIdx.x;
  if (e >= E + N) return;
  int src, dst;
  if (e < E){ src = ei[e]; dst = ei[E + e]; } else { src = dst = e - E; }
  int pos = atomicAdd(&cursor[dst], 1);
  csr_src[pos] = src;
}

// ---------------- GEMM: out[N,OUT] = A[N,K] @ W[K,OUT] ----------------
template<int K, int OUT>
__global__ __launch_bounds__(256) void k_gemm(const float* __restrict__ A, const float* __restrict__ W,
                                              float* __restrict__ out, int N)
{
  constexpr int ROWS = 16;
  constexpr int CG = OUT / 4;        // col groups (4 cols per thread)
  constexpr int RG = 256 / CG;       // row groups
  constexpr int RP = ROWS / RG;      // rows per thread
  __shared__ float At[K][ROWS + 1];  // +1 pad: conflict-free transposed store
  const int row0 = blockIdx.x * ROWS;
  const int tid = (int)threadIdx.x;

  for (int idx = tid; idx < ROWS * K; idx += 256){
    int r = idx / K;
    int k = idx - r * K;
    int row = row0 + r;
    At[k][r] = (row < N) ? A[(size_t)row * K + k] : 0.f;
  }
  __syncthreads();

  const int cg = tid % CG;
  const int rg = tid / CG;
  float acc[RP][4];
  #pragma unroll
  for (int r = 0; r < RP; r++){ acc[r][0] = acc[r][1] = acc[r][2] = acc[r][3] = 0.f; }

  const float* Wb = W + cg * 4;
  #pragma unroll 4
  for (int k = 0; k < K; k++){
    const float4 w = *reinterpret_cast<const float4*>(Wb + (size_t)k * OUT);
    #pragma unroll
    for (int r = 0; r < RP; r++){
      float a = At[k][rg * RP + r];
      acc[r][0] = fmaf(a, w.x, acc[r][0]);
      acc[r][1] = fmaf(a, w.y, acc[r][1]);
      acc[r][2] = fmaf(a, w.z, acc[r][2]);
      acc[r][3] = fmaf(a, w.w, acc[r][3]);
    }
  }
  #pragma unroll
  for (int r = 0; r < RP; r++){
    int row = row0 + rg * RP + r;
    if (row < N){
      float4 v = make_float4(acc[r][0], acc[r][1], acc[r][2], acc[r][3]);
      *reinterpret_cast<float4*>(&out[(size_t)row * OUT + cg * 4]) = v;
    }
  }
}

// ---------------- attention coefficients: al/ar[n,h] = sum_c xl[n,h,c]*a[h,c] ----------------
template<int H, int C>
__global__ __launch_bounds__(256) void k_attn_coef(const float* __restrict__ xl,
    const float* __restrict__ asrc, const float* __restrict__ adst,
    float* __restrict__ al, float* __restrict__ ar)
{
  constexpr int DIM = H * C;
  const int n = blockIdx.x;
  const int t = (int)threadIdx.x;
  __shared__ float sa[256], sb[256];
  float pa = 0.f, pb = 0.f;
  if (t < DIM){
    float x = xl[(size_t)n * DIM + t];
    pa = x * asrc[t];
    pb = x * adst[t];
  }
  sa[t] = pa; sb[t] = pb;
  __syncthreads();
  #pragma unroll
  for (int off = C / 2; off > 0; off >>= 1){
    if (t < DIM && (t & (C - 1)) < off){
      sa[t] += sa[t + off];
      sb[t] += sb[t + off];
    }
    __syncthreads();
  }
  if (t < DIM && (t & (C - 1)) == 0){
    al[n * H + t / C] = sa[t];
    ar[n * H + t / C] = sb[t];
  }
}

// ---------------- per-node gather: softmax over incoming edges, aggregate, +bias, LN, ReLU ----------------
template<int H, int C, int DIM>
__global__ __launch_bounds__(256) void k_agg(const float* __restrict__ xl,
    const float* __restrict__ al, const float* __restrict__ ar,
    const int* __restrict__ row_ptr, const int* __restrict__ csr_src,
    const float* __restrict__ bias, const float* __restrict__ gamma, const float* __restrict__ beta,
    float* __restrict__ out)
{
  const int n = blockIdx.x;
  const int tid = (int)threadIdx.x;
  const int start = row_ptr[n];
  const int end = row_ptr[n + 1];
  __shared__ float m_s[H], s_s[H];

  if (tid < 64){  // wave 0: segment max then segment sum (per head)
    float arv[H], mx[H], sm[H];
    #pragma unroll
    for (int h = 0; h < H; h++){ arv[h] = ar[n * H + h]; mx[h] = -1e30f; sm[h] = 0.f; }
    for (int i = start + tid; i < end; i += 64){
      int src = csr_src[i];
      #pragma unroll
      for (int h = 0; h < H; h++){
        float e = al[src * H + h] + arv[h];
        e = e > 0.f ? e : 0.2f * e;
        mx[h] = fmaxf(mx[h], e);
      }
    }
    #pragma unroll
    for (int h = 0; h < H; h++){
      #pragma unroll
      for (int off = 32; off > 0; off >>= 1) mx[h] = fmaxf(mx[h], __shfl_xor(mx[h], off));
    }
    for (int i = start + tid; i < end; i += 64){
      int src = csr_src[i];
      #pragma unroll
      for (int h = 0; h < H; h++){
        float e = al[src * H + h] + arv[h];
        e = e > 0.f ? e : 0.2f * e;
        sm[h] += __expf(e - mx[h]);
      }
    }
    #pragma unroll
    for (int h = 0; h < H; h++){
      #pragma unroll
      for (int off = 32; off > 0; off >>= 1) sm[h] += __shfl_xor(sm[h], off);
    }
    if (tid == 0){
      #pragma unroll
      for (int h = 0; h < H; h++){ m_s[h] = mx[h]; s_s[h] = sm[h] + 1e-16f; }
    }
  }
  __syncthreads();

  float acc = 0.f;
  if (tid < DIM){
    const int h = tid / C;
    const float mh = m_s[h];
    const float inv_s = 1.f / s_s[h];
    const float arv = ar[n * H + h];
    for (int i = start; i < end; i++){
      int src = csr_src[i];
      float e = al[src * H + h] + arv;
      e = e > 0.f ? e : 0.2f * e;
      float alpha = __expf(e - mh) * inv_s;
      acc = fmaf(alpha, xl[(size_t)src * DIM + tid], acc);
    }
    acc += bias[tid];
  }

  // fused LayerNorm(+ReLU) over DIM
  const int lane = tid & 63, wid = tid >> 6;
  float v = (tid < DIM) ? acc : 0.f;
  float v2 = v * v;
  #pragma unroll
  for (int off = 32; off > 0; off >>= 1){ v += __shfl_xor(v, off); v2 += __shfl_xor(v2, off); }
  __shared__ float rs[4], rs2[4];
  if (lane == 0){ rs[wid] = v; rs2[wid] = v2; }
  __syncthreads();
  __shared__ float mu_s, rstd_s;
  if (tid == 0){
    float S = 0.f, S2 = 0.f;
    #pragma unroll
    for (int w = 0; w < DIM / 64; w++){ S += rs[w]; S2 += rs2[w]; }
    float mu = S / DIM;
    float var = S2 / DIM - mu * mu;
    mu_s = mu;
    rstd_s = rsqrtf(var + EPS_LN);
  }
  __syncthreads();
  if (tid < DIM){
    float y = (acc - mu_s) * rstd_s * gamma[tid] + beta[tid];
    out[(size_t)n * DIM + tid] = fmaxf(y, 0.f);
  }
}

// ---------------- pooling ----------------
__global__ void k_count(const int* __restrict__ batch, int* __restrict__ cnt, int N){
  int i = blockIdx.x * 256 + threadIdx.x;
  if (i < N) atomicAdd(&cnt[batch[i]], 1);
}

__global__ __launch_bounds__(128) void k_pool(const float* __restrict__ h, const int* __restrict__ batch,
    float* __restrict__ pool_sum, unsigned* __restrict__ pool_max, int N){
  const int c = (int)threadIdx.x;  // 0..127
  int n0 = blockIdx.x * 256;
  if (n0 >= N) return;
  int n1 = min(n0 + 256, N);
  float s = 0.f, mx = 0.f;           // post-ReLU values are >= 0
  int cur = batch[n0];
  for (int n = n0; n < n1; n++){
    int b = batch[n];
    if (b != cur){
      atomicAdd(&pool_sum[cur * 128 + c], s);
      atomicMax(&pool_max[cur * 128 + c], __float_as_uint(mx));
      s = 0.f; mx = 0.f; cur = b;
    }
    float v = h[(size_t)n * 128 + c];
    s += v; mx = fmaxf(mx, v);
  }
  atomicAdd(&pool_sum[cur * 128 + c], s);
  atomicMax(&pool_max[cur * 128 + c], __float_as_uint(mx));
}

__global__ __launch_bounds__(128) void k_final(const float* __restrict__ pool_sum,
    const unsigned* __restrict__ pool_max, const int* __restrict__ cnt,
    const float* __restrict__ Wp, const float* __restrict__ bp, float* __restrict__ out){
  const int g = blockIdx.x;
  const int j = (int)threadIdx.x;
  float inv = 1.f / fmaxf((float)cnt[g], 1.f);
  float acc = bp[j];
  #pragma unroll 4
  for (int k = 0; k < 128; k++)
    acc = fmaf(pool_sum[g * 128 + k] * inv, Wp[k * 128 + j], acc);
  #pragma unroll 4
  for (int k = 0; k < 128; k++)
    acc = fmaf(__uint_as_float(pool_max[g * 128 + k]), Wp[(128 + k) * 128 + j], acc);
  out[g * 128 + j] = acc;
}

// ---------------- launch ----------------
extern "C" void kernel_launch(void* const* d_in, const int* in_sizes, int n_in,
                              void* d_out, int out_size, void* d_ws, size_t ws_size,
                              hipStream_t stream){
  const float* x     = (const float*)d_in[0];
  const int*   ei    = (const int*)d_in[1];
  const int*   batch = (const int*)d_in[2];
  const float* W1    = (const float*)d_in[3];
  const float* asrc1 = (const float*)d_in[4];
  const float* adst1 = (const float*)d_in[5];
  const float* b1    = (const float*)d_in[6];
  const float* g1    = (const float*)d_in[7];
  const float* be1   = (const float*)d_in[8];
  const float* W2    = (const float*)d_in[9];
  const float* asrc2 = (const float*)d_in[10];
  const float* adst2 = (const float*)d_in[11];
  const float* b2    = (const float*)d_in[12];
  const float* g2    = (const float*)d_in[13];
  const float* be2   = (const float*)d_in[14];
  const float* W3    = (const float*)d_in[15];
  const float* asrc3 = (const float*)d_in[16];
  const float* adst3 = (const float*)d_in[17];
  const float* b3    = (const float*)d_in[18];
  const float* g3    = (const float*)d_in[19];
  const float* be3   = (const float*)d_in[20];
  const float* Wp    = (const float*)d_in[21];
  const float* bp    = (const float*)d_in[22];

  const int N = in_sizes[0] / 128;
  const int E = in_sizes[1] / 2;
  const int G = out_size / 128;
  const int EN = E + N;

  char* ws = (char*)d_ws;
  size_t off = 0;
  auto alloc = [&](size_t bytes) -> char* {
    char* p = ws + off;
    off = (off + bytes + 255) & ~(size_t)255;
    return p;
  };
  float*    xbufA    = (float*)alloc((size_t)N * 256 * 4);   // xl
  float*    xbufB    = (float*)alloc((size_t)N * 256 * 4);   // layer output h
  float*    al       = (float*)alloc((size_t)N * 4 * 4);
  float*    ar       = (float*)alloc((size_t)N * 4 * 4);
  int*      deg      = (int*)alloc((size_t)N * 4);
  int*      row_ptr  = (int*)alloc((size_t)(N + 1) * 4);
  int*      cursor   = (int*)alloc((size_t)N * 4);
  int*      csr_src  = (int*)alloc((size_t)EN * 4);
  int*      cnt      = (int*)alloc((size_t)G * 4);
  float*    pool_sum = (float*)alloc((size_t)G * 128 * 4);
  unsigned* pool_max = (unsigned*)alloc((size_t)G * 128 * 4);

  hipMemsetAsync(deg, 0, (size_t)N * 4, stream);
  hipMemsetAsync(cnt, 0, (size_t)G * 4, stream);
  hipMemsetAsync(pool_sum, 0, (size_t)G * 128 * 4, stream);
  hipMemsetAsync(pool_max, 0, (size_t)G * 128 * 4, stream);

  // CSR build (shared by all 3 layers)
  k_deg<<<(EN + 255) / 256, 256, 0, stream>>>(ei, deg, E, N);
  k_scan<<<1, 1024, 0, stream>>>(deg, row_ptr, cursor, N);
  k_scatter<<<(EN + 255) / 256, 256, 0, stream>>>(ei, cursor, csr_src, E, N);

  // Layer 1: 128 -> 256, H=4, C=64
  k_gemm<128, 256><<<(N + 15) / 16, 256, 0, stream>>>(x, W1, xbufA, N);
  k_attn_coef<4, 64><<<N, 256, 0, stream>>>(xbufA, asrc1, adst1, al, ar);
  k_agg<4, 64, 256><<<N, 256, 0, stream>>>(xbufA, al, ar, row_ptr, csr_src, b1, g1, be1, xbufB);

  // Layer 2: 256 -> 256, H=4, C=64
  k_gemm<256, 256><<<(N + 15) / 16, 256, 0, stream>>>(xbufB, W2, xbufA, N);
  k_attn_coef<4, 64><<<N, 256, 0, stream>>>(xbufA, asrc2, adst2, al, ar);
  k_agg<4, 64, 256><<<N, 256, 0, stream>>>(xbufA, al, ar, row_ptr, csr_src, b2, g2, be2, xbufB);

  // Layer 3: 256 -> 128, H=1, C=128
  k_gemm<256, 128><<<(N + 15) / 16, 256, 0, stream>>>(xbufB, W3, xbufA, N);
  k_attn_coef<1, 128><<<N, 256, 0, stream>>>(xbufA, asrc3, adst3, al, ar);
  k_agg<1, 128, 128><<<N, 256, 0, stream>>>(xbufA, al, ar, row_ptr, csr_src, b3, g3, be3, xbufB);

  // Pooling + final projection
  k_count<<<(N + 255) / 256, 256, 0, stream>>>(batch, cnt, N);
  k_pool<<<(N + 255) / 256, 128, 0, stream>>>(xbufB, batch, pool_sum, pool_max, N);
  k_final<<<G, 128, 0, stream>>>(pool_sum, pool_max, cnt, Wp, bp, (float*)d_out);
}

// Round 2
// 1644.622 us; speedup vs baseline: 1.0008x; 1.0008x over previous
//
#include <hip/hip_runtime.h>

#define EPS_LN 1e-5f

// ---------------- CSR build (dst-indexed) ----------------
__global__ void k_deg(const int* __restrict__ ei, int* __restrict__ deg, int E, int N){
  int e = blockIdx.x * 256 + threadIdx.x;
  if (e >= E + N) return;
  int dst = (e < E) ? ei[E + e] : (e - E);   // self loops appended
  atomicAdd(&deg[dst], 1);
}

__global__ __launch_bounds__(1024) void k_scan(const int* __restrict__ deg, int* __restrict__ row_ptr,
                                               int* __restrict__ cursor, int n){
  __shared__ int lds[1024];
  __shared__ int carry;
  if (threadIdx.x == 0){ carry = 0; row_ptr[0] = 0; }
  __syncthreads();
  for (int base = 0; base < n; base += 1024){
    int i = base + (int)threadIdx.x;
    int v = (i < n) ? deg[i] : 0;
    lds[threadIdx.x] = v;
    __syncthreads();
    for (int off = 1; off < 1024; off <<= 1){
      int t = (threadIdx.x >= (unsigned)off) ? lds[threadIdx.x - off] : 0;
      __syncthreads();
      lds[threadIdx.x] += t;
      __syncthreads();
    }
    int inc = lds[threadIdx.x] + carry;
    if (i < n){ row_ptr[i + 1] = inc; cursor[i] = inc - v; }
    __syncthreads();
    if (threadIdx.x == 1023) carry = inc;
    __syncthreads();
  }
}

__global__ void k_scatter(const int* __restrict__ ei, int* __restrict__ cursor,
                          int* __restrict__ csr_src, int E, int N){
  int e = blockIdx.x * 256 + threadIdx.x;
  if (e >= E + N) return;
  int src, dst;
  if (e < E){ src = ei[e]; dst = ei[E + e]; } else { src = dst = e - E; }
  int pos = atomicAdd(&cursor[dst], 1);
  csr_src[pos] = src;
}

// ---------------- GEMM: out[N,OUT] = A[N,K] @ W[K,OUT] ----------------
template<int K, int OUT>
__global__ __launch_bounds__(256) void k_gemm(const float* __restrict__ A, const float* __restrict__ W,
                                              float* __restrict__ out, int N)
{
  constexpr int ROWS = 16;
  constexpr int CG = OUT / 4;        // col groups (4 cols per thread)
  constexpr int RG = 256 / CG;       // row groups
  constexpr int RP = ROWS / RG;      // rows per thread
  __shared__ float At[K][ROWS + 1];  // +1 pad: conflict-free transposed store
  const int row0 = blockIdx.x * ROWS;
  const int tid = (int)threadIdx.x;

  for (int idx = tid; idx < ROWS * K; idx += 256){
    int r = idx / K;
    int k = idx - r * K;
    int row = row0 + r;
    At[k][r] = (row < N) ? A[(size_t)row * K + k] : 0.f;
  }
  __syncthreads();

  const int cg = tid % CG;
  const int rg = tid / CG;
  float acc[RP][4];
  #pragma unroll
  for (int r = 0; r < RP; r++){ acc[r][0] = acc[r][1] = acc[r][2] = acc[r][3] = 0.f; }

  const float* Wb = W + cg * 4;
  #pragma unroll 4
  for (int k = 0; k < K; k++){
    const float4 w = *reinterpret_cast<const float4*>(Wb + (size_t)k * OUT);
    #pragma unroll
    for (int r = 0; r < RP; r++){
      float a = At[k][rg * RP + r];
      acc[r][0] = fmaf(a, w.x, acc[r][0]);
      acc[r][1] = fmaf(a, w.y, acc[r][1]);
      acc[r][2] = fmaf(a, w.z, acc[r][2]);
      acc[r][3] = fmaf(a, w.w, acc[r][3]);
    }
  }
  #pragma unroll
  for (int r = 0; r < RP; r++){
    int row = row0 + rg * RP + r;
    if (row < N){
      float4 v = make_float4(acc[r][0], acc[r][1], acc[r][2], acc[r][3]);
      *reinterpret_cast<float4*>(&out[(size_t)row * OUT + cg * 4]) = v;
    }
  }
}

// ---------------- attention coefficients: al/ar[n,h] = sum_c xl[n,h,c]*a[h,c] ----------------
template<int H, int C>
__global__ __launch_bounds__(256) void k_attn_coef(const float* __restrict__ xl,
    const float* __restrict__ asrc, const float* __restrict__ adst,
    float* __restrict__ al, float* __restrict__ ar)
{
  constexpr int DIM = H * C;
  const int n = blockIdx.x;
  const int t = (int)threadIdx.x;
  __shared__ float sa[256], sb[256];
  float pa = 0.f, pb = 0.f;
  if (t < DIM){
    float x = xl[(size_t)n * DIM + t];
    pa = x * asrc[t];
    pb = x * adst[t];
  }
  sa[t] = pa; sb[t] = pb;
  __syncthreads();
  #pragma unroll
  for (int off = C / 2; off > 0; off >>= 1){
    if (t < DIM && (t & (C - 1)) < off){
      sa[t] += sa[t + off];
      sb[t] += sb[t + off];
    }
    __syncthreads();
  }
  if (t < DIM && (t & (C - 1)) == 0){
    al[n * H + t / C] = sa[t];
    ar[n * H + t / C] = sb[t];
  }
}

// ---------------- per-node gather: softmax over incoming edges, aggregate, +bias, LN, ReLU ----------------
template<int H, int C, int DIM>
__global__ __launch_bounds__(256) void k_agg(const float* __restrict__ xl,
    const float* __restrict__ al, const float* __restrict__ ar,
    const int* __restrict__ row_ptr, const int* __restrict__ csr_src,
    const float* __restrict__ bias, const float* __restrict__ gamma, const float* __restrict__ beta,
    float* __restrict__ out)
{
  const int n = blockIdx.x;
  const int tid = (int)threadIdx.x;
  const int start = row_ptr[n];
  const int end = row_ptr[n + 1];
  __shared__ float m_s[H], s_s[H];

  if (tid < 64){  // wave 0: segment max then segment sum (per head)
    float arv[H], mx[H], sm[H];
    #pragma unroll
    for (int h = 0; h < H; h++){ arv[h] = ar[n * H + h]; mx[h] = -1e30f; sm[h] = 0.f; }
    for (int i = start + tid; i < end; i += 64){
      int src = csr_src[i];
      #pragma unroll
      for (int h = 0; h < H; h++){
        float e = al[src * H + h] + arv[h];
        e = e > 0.f ? e : 0.2f * e;
        mx[h] = fmaxf(mx[h], e);
      }
    }
    #pragma unroll
    for (int h = 0; h < H; h++){
      #pragma unroll
      for (int off = 32; off > 0; off >>= 1) mx[h] = fmaxf(mx[h], __shfl_xor(mx[h], off));
    }
    for (int i = start + tid; i < end; i += 64){
      int src = csr_src[i];
      #pragma unroll
      for (int h = 0; h < H; h++){
        float e = al[src * H + h] + arv[h];
        e = e > 0.f ? e : 0.2f * e;
        sm[h] += __expf(e - mx[h]);
      }
    }
    #pragma unroll
    for (int h = 0; h < H; h++){
      #pragma unroll
      for (int off = 32; off > 0; off >>= 1) sm[h] += __shfl_xor(sm[h], off);
    }
    if (tid == 0){
      #pragma unroll
      for (int h = 0; h < H; h++){ m_s[h] = mx[h]; s_s[h] = sm[h] + 1e-16f; }
    }
  }
  __syncthreads();

  float acc = 0.f;
  if (tid < DIM){
    const int h = tid / C;
    const float mh = m_s[h];
    const float inv_s = 1.f / s_s[h];
    const float arv = ar[n * H + h];
    for (int i = start; i < end; i++){
      int src = csr_src[i];
      float e = al[src * H + h] + arv;
      e = e > 0.f ? e : 0.2f * e;
      float alpha = __expf(e - mh) * inv_s;
      acc = fmaf(alpha, xl[(size_t)src * DIM + tid], acc);
    }
    acc += bias[tid];
  }

  // fused LayerNorm(+ReLU) over DIM
  const int lane = tid & 63, wid = tid >> 6;
  float v = (tid < DIM) ? acc : 0.f;
  float v2 = v * v;
  #pragma unroll
  for (int off = 32; off > 0; off >>= 1){ v += __shfl_xor(v, off); v2 += __shfl_xor(v2, off); }
  __shared__ float rs[4], rs2[4];
  if (lane == 0){ rs[wid] = v; rs2[wid] = v2; }
  __syncthreads();
  __shared__ float mu_s, rstd_s;
  if (tid == 0){
    float S = 0.f, S2 = 0.f;
    #pragma unroll
    for (int w = 0; w < DIM / 64; w++){ S += rs[w]; S2 += rs2[w]; }
    float mu = S / DIM;
    float var = S2 / DIM - mu * mu;
    mu_s = mu;
    rstd_s = rsqrtf(var + EPS_LN);
  }
  __syncthreads();
  if (tid < DIM){
    float y = (acc - mu_s) * rstd_s * gamma[tid] + beta[tid];
    out[(size_t)n * DIM + tid] = fmaxf(y, 0.f);
  }
}

// ---------------- pooling ----------------
__global__ void k_count(const int* __restrict__ batch, int* __restrict__ cnt, int N){
  int i = blockIdx.x * 256 + threadIdx.x;
  if (i < N) atomicAdd(&cnt[batch[i]], 1);
}

__global__ __launch_bounds__(128) void k_pool(const float* __restrict__ h, const int* __restrict__ batch,
    float* __restrict__ pool_sum, unsigned* __restrict__ pool_max, int N){
  const int c = (int)threadIdx.x;  // 0..127
  int n0 = blockIdx.x * 256;
  if (n0 >= N) return;
  int n1 = min(n0 + 256, N);
  float s = 0.f, mx = 0.f;           // post-ReLU values are >= 0
  int cur = batch[n0];
  for (int n = n0; n < n1; n++){
    int b = batch[n];
    if (b != cur){
      atomicAdd(&pool_sum[cur * 128 + c], s);
      atomicMax(&pool_max[cur * 128 + c], __float_as_uint(mx));
      s = 0.f; mx = 0.f; cur = b;
    }
    float v = h[(size_t)n * 128 + c];
    s += v; mx = fmaxf(mx, v);
  }
  atomicAdd(&pool_sum[cur * 128 + c], s);
  atomicMax(&pool_max[cur * 128 + c], __float_as_uint(mx));
}

__global__ __launch_bounds__(128) void k_final(const float* __restrict__ pool_sum,
    const unsigned* __restrict__ pool_max, const int* __restrict__ cnt,
    const float* __restrict__ Wp, const float* __restrict__ bp, float* __restrict__ out){
  const int g = blockIdx.x;
  const int j = (int)threadIdx.x;
  float inv = 1.f / fmaxf((float)cnt[g], 1.f);
  float acc = bp[j];
  #pragma unroll 4
  for (int k = 0; k < 128; k++)
    acc = fmaf(pool_sum[g * 128 + k] * inv, Wp[k * 128 + j], acc);
  #pragma unroll 4
  for (int k = 0; k < 128; k++)
    acc = fmaf(__uint_as_float(pool_max[g * 128 + k]), Wp[(128 + k) * 128 + j], acc);
  out[g * 128 + j] = acc;
}

// ---------------- launch ----------------
extern "C" void kernel_launch(void* const* d_in, const int* in_sizes, int n_in,
                              void* d_out, int out_size, void* d_ws, size_t ws_size,
                              hipStream_t stream){
  const float* x     = (const float*)d_in[0];
  const int*   ei    = (const int*)d_in[1];
  const int*   batch = (const int*)d_in[2];
  const float* W1    = (const float*)d_in[3];
  const float* asrc1 = (const float*)d_in[4];
  const float* adst1 = (const float*)d_in[5];
  const float* b1    = (const float*)d_in[6];
  const float* g1    = (const float*)d_in[7];
  const float* be1   = (const float*)d_in[8];
  const float* W2    = (const float*)d_in[9];
  const float* asrc2 = (const float*)d_in[10];
  const float* adst2 = (const float*)d_in[11];
  const float* b2    = (const float*)d_in[12];
  const float* g2    = (const float*)d_in[13];
  const float* be2   = (const float*)d_in[14];
  const float* W3    = (const float*)d_in[15];
  const float* asrc3 = (const float*)d_in[16];
  const float* adst3 = (const float*)d_in[17];
  const float* b3    = (const float*)d_in[18];
  const float* g3    = (const float*)d_in[19];
  const float* be3   = (const float*)d_in[20];
  const float* Wp    = (const float*)d_in[21];
  const float* bp    = (const float*)d_in[22];

  const int N = in_sizes[0] / 128;
  const int E = in_sizes[1] / 2;
  const int G = out_size / 128;
  const int EN = E + N;

  char* ws = (char*)d_ws;
  size_t off = 0;
  auto alloc = [&](size_t bytes) -> char* {
    char* p = ws + off;
    off = (off + bytes + 255) & ~(size_t)255;
    return p;
  };
  float*    xbufA    = (float*)alloc((size_t)N * 256 * 4);   // xl
  float*    xbufB    = (float*)alloc((size_t)N * 256 * 4);   // layer output h
  float*    al       = (float*)alloc((size_t)N * 4 * 4);
  float*    ar       = (float*)alloc((size_t)N * 4 * 4);
  int*      deg      = (int*)alloc((size_t)N * 4);
  int*      row_ptr  = (int*)alloc((size_t)(N + 1) * 4);
  int*      cursor   = (int*)alloc((size_t)N * 4);
  int*      csr_src  = (int*)alloc((size_t)EN * 4);
  int*      cnt      = (int*)alloc((size_t)G * 4);
  float*    pool_sum = (float*)alloc((size_t)G * 128 * 4);
  unsigned* pool_max = (unsigned*)alloc((size_t)G * 128 * 4);

  hipMemsetAsync(deg, 0, (size_t)N * 4, stream);
  hipMemsetAsync(cnt, 0, (size_t)G * 4, stream);
  hipMemsetAsync(pool_sum, 0, (size_t)G * 128 * 4, stream);
  hipMemsetAsync(pool_max, 0, (size_t)G * 128 * 4, stream);

  // CSR build (shared by all 3 layers)
  k_deg<<<(EN + 255) / 256, 256, 0, stream>>>(ei, deg, E, N);
  k_scan<<<1, 1024, 0, stream>>>(deg, row_ptr, cursor, N);
  k_scatter<<<(EN + 255) / 256, 256, 0, stream>>>(ei, cursor, csr_src, E, N);

  // Layer 1: 128 -> 256, H=4, C=64
  k_gemm<128, 256><<<(N + 15) / 16, 256, 0, stream>>>(x, W1, xbufA, N);
  k_attn_coef<4, 64><<<N, 256, 0, stream>>>(xbufA, asrc1, adst1, al, ar);
  k_agg<4, 64, 256><<<N, 256, 0, stream>>>(xbufA, al, ar, row_ptr, csr_src, b1, g1, be1, xbufB);

  // Layer 2: 256 -> 256, H=4, C=64
  k_gemm<256, 256><<<(N + 15) / 16, 256, 0, stream>>>(xbufB, W2, xbufA, N);
  k_attn_coef<4, 64><<<N, 256, 0, stream>>>(xbufA, asrc2, adst2, al, ar);
  k_agg<4, 64, 256><<<N, 256, 0, stream>>>(xbufA, al, ar, row_ptr, csr_src, b2, g2, be2, xbufB);

  // Layer 3: 256 -> 128, H=1, C=128
  k_gemm<256, 128><<<(N + 15) / 16, 256, 0, stream>>>(xbufB, W3, xbufA, N);
  k_attn_coef<1, 128><<<N, 256, 0, stream>>>(xbufA, asrc3, adst3, al, ar);
  k_agg<1, 128, 128><<<N, 256, 0, stream>>>(xbufA, al, ar, row_ptr, csr_src, b3, g3, be3, xbufB);

  // Pooling + final projection
  k_count<<<(N + 255) / 256, 256, 0, stream>>>(batch, cnt, N);
  k_pool<<<(N + 255) / 256, 128, 0, stream>>>(xbufB, batch, pool_sum, pool_max, N);
  k_final<<<G, 128, 0, stream>>>(pool_sum, pool_max, cnt, Wp, bp, (float*)d_out);
}

// Round 3
// 1034.756 us; speedup vs baseline: 1.5907x; 1.5894x over previous
//
#include <hip/hip_runtime.h>

#define EPS_LN 1e-5f
typedef unsigned int uint;

__device__ inline float bf2f(ushort h){ return __uint_as_float(((uint)h) << 16); }
__device__ inline ushort f2bf(float f){
  uint u = __float_as_uint(f);
  u += 0x7fffu + ((u >> 16) & 1u);   // round-to-nearest-even
  return (ushort)(u >> 16);
}

// ---------------- CSR build (dst-indexed) ----------------
__global__ void k_deg(const int* __restrict__ ei, int* __restrict__ deg, int E, int N){
  int e = blockIdx.x * 256 + threadIdx.x;
  if (e >= E + N) return;
  int dst = (e < E) ? ei[E + e] : (e - E);   // self loops appended
  atomicAdd(&deg[dst], 1);
}

__global__ __launch_bounds__(1024) void k_scan(const int* __restrict__ deg, int* __restrict__ row_ptr,
                                               int* __restrict__ cursor, int n){
  __shared__ int lds[1024];
  __shared__ int carry;
  if (threadIdx.x == 0){ carry = 0; row_ptr[0] = 0; }
  __syncthreads();
  for (int base = 0; base < n; base += 1024){
    int i = base + (int)threadIdx.x;
    int v = (i < n) ? deg[i] : 0;
    lds[threadIdx.x] = v;
    __syncthreads();
    for (int off = 1; off < 1024; off <<= 1){
      int t = (threadIdx.x >= (unsigned)off) ? lds[threadIdx.x - off] : 0;
      __syncthreads();
      lds[threadIdx.x] += t;
      __syncthreads();
    }
    int inc = lds[threadIdx.x] + carry;
    if (i < n){ row_ptr[i + 1] = inc; cursor[i] = inc - v; }
    __syncthreads();
    if (threadIdx.x == 1023) carry = inc;
    __syncthreads();
  }
}

__global__ void k_scatter(const int* __restrict__ ei, int* __restrict__ cursor,
                          int* __restrict__ csr_src, int E, int N){
  int e = blockIdx.x * 256 + threadIdx.x;
  if (e >= E + N) return;
  int src, dst;
  if (e < E){ src = ei[e]; dst = ei[E + e]; } else { src = dst = e - E; }
  int pos = atomicAdd(&cursor[dst], 1);
  csr_src[pos] = src;
}

// ---------------- GEMM: out[N,OUT](bf16) = A[N,K](f32) @ W[K,OUT](f32) ----------------
template<int K, int OUT>
__global__ __launch_bounds__(256) void k_gemm(const float* __restrict__ A, const float* __restrict__ W,
                                              ushort* __restrict__ out, int N)
{
  constexpr int ROWS = 16;
  constexpr int CG = OUT / 4;        // col groups (4 cols per thread)
  constexpr int RG = 256 / CG;       // row groups
  constexpr int RP = ROWS / RG;      // rows per thread
  __shared__ float At[K][ROWS + 1];
  const int row0 = blockIdx.x * ROWS;
  const int tid = (int)threadIdx.x;

  for (int idx = tid; idx < ROWS * K; idx += 256){
    int r = idx / K;
    int k = idx - r * K;
    int row = row0 + r;
    At[k][r] = (row < N) ? A[(size_t)row * K + k] : 0.f;
  }
  __syncthreads();

  const int cg = tid % CG;
  const int rg = tid / CG;
  float acc[RP][4];
  #pragma unroll
  for (int r = 0; r < RP; r++){ acc[r][0] = acc[r][1] = acc[r][2] = acc[r][3] = 0.f; }

  const float* Wb = W + cg * 4;
  #pragma unroll 4
  for (int k = 0; k < K; k++){
    const float4 w = *reinterpret_cast<const float4*>(Wb + (size_t)k * OUT);
    #pragma unroll
    for (int r = 0; r < RP; r++){
      float a = At[k][rg * RP + r];
      acc[r][0] = fmaf(a, w.x, acc[r][0]);
      acc[r][1] = fmaf(a, w.y, acc[r][1]);
      acc[r][2] = fmaf(a, w.z, acc[r][2]);
      acc[r][3] = fmaf(a, w.w, acc[r][3]);
    }
  }
  #pragma unroll
  for (int r = 0; r < RP; r++){
    int row = row0 + rg * RP + r;
    if (row < N){
      ushort4 v;
      v.x = f2bf(acc[r][0]); v.y = f2bf(acc[r][1]);
      v.z = f2bf(acc[r][2]); v.w = f2bf(acc[r][3]);
      *reinterpret_cast<ushort4*>(&out[(size_t)row * OUT + cg * 4]) = v;
    }
  }
}

// ---------------- attention coefficients from bf16 xl ----------------
template<int H, int DIM>
__global__ __launch_bounds__(256) void k_coef(const ushort* __restrict__ xl,
    const float* __restrict__ asrc, const float* __restrict__ adst,
    float* __restrict__ al, float* __restrict__ ar, int N)
{
  constexpr int EPL = DIM / 64;       // elems per lane (4 or 2)
  constexpr int C = DIM / H;
  constexpr int LG = C / EPL;         // lanes per head group
  const int lane = (int)threadIdx.x & 63;
  const int n = blockIdx.x * 4 + ((int)threadIdx.x >> 6);
  if (n >= N) return;
  const size_t base = (size_t)n * DIM + lane * EPL;
  ushort xv[EPL];
  if constexpr (EPL == 4){ *reinterpret_cast<uint2*>(xv) = *reinterpret_cast<const uint2*>(&xl[base]); }
  else                   { *reinterpret_cast<uint*>(xv)  = *reinterpret_cast<const uint*>(&xl[base]); }
  float pa = 0.f, pb = 0.f;
  #pragma unroll
  for (int j = 0; j < EPL; j++){
    float x = bf2f(xv[j]);
    pa = fmaf(x, asrc[lane * EPL + j], pa);
    pb = fmaf(x, adst[lane * EPL + j], pb);
  }
  #pragma unroll
  for (int off = 1; off < LG; off <<= 1){ pa += __shfl_xor(pa, off); pb += __shfl_xor(pb, off); }
  if ((lane & (LG - 1)) == 0){
    int h = lane / LG;
    al[(size_t)n * H + h] = pa;
    ar[(size_t)n * H + h] = pb;
  }
}

// ---------------- per-node gather: softmax + aggregate + bias + LN + ReLU ----------------
// NT = DIM/2 threads; each thread owns 2 output columns.
template<int H, int DIM>
__global__ __launch_bounds__(DIM / 2) void k_agg2(
    const ushort* __restrict__ xl,
    const float* __restrict__ al, const float* __restrict__ ar,
    const int* __restrict__ row_ptr, const int* __restrict__ csr_src,
    const float* __restrict__ bias, const float* __restrict__ gamma, const float* __restrict__ beta,
    float* __restrict__ out)
{
  constexpr int NT = DIM / 2;
  constexpr int NW = NT / 64;
  constexpr int C = DIM / H;
  const int n = blockIdx.x;
  const int tid = (int)threadIdx.x;
  const int start = row_ptr[n], end = row_ptr[n + 1];

  __shared__ int   sh_src[64];
  __shared__ float sh_alpha[H][64];
  __shared__ float sh_m[H], sh_is[H], sh_ar[H];
  __shared__ float red[(NW > 1 ? NW : 1) * H];
  __shared__ float r1[NW], r2[NW];
  __shared__ float rmu, rstd;

  if (tid < H) sh_ar[tid] = ar[(size_t)n * H + tid];

  float arv[H];
  #pragma unroll
  for (int h = 0; h < H; h++) arv[h] = ar[(size_t)n * H + h];

  // ---- pass A: per-head max of leaky(e) ----
  float mx[H];
  #pragma unroll
  for (int h = 0; h < H; h++) mx[h] = -1e30f;
  for (int i = start + tid; i < end; i += NT){
    int src = csr_src[i];
    if constexpr (H == 4){
      float4 a4 = *reinterpret_cast<const float4*>(&al[(size_t)src * 4]);
      float ev[4] = {a4.x + arv[0], a4.y + arv[1], a4.z + arv[2], a4.w + arv[3]};
      #pragma unroll
      for (int h = 0; h < 4; h++){ float e = ev[h]; e = e > 0.f ? e : 0.2f * e; mx[h] = fmaxf(mx[h], e); }
    } else {
      float e = al[src] + arv[0]; e = e > 0.f ? e : 0.2f * e; mx[0] = fmaxf(mx[0], e);
    }
  }
  #pragma unroll
  for (int h = 0; h < H; h++){
    #pragma unroll
    for (int off = 32; off; off >>= 1) mx[h] = fmaxf(mx[h], __shfl_xor(mx[h], off));
  }
  if constexpr (NW > 1){
    if ((tid & 63) == 0){
      #pragma unroll
      for (int h = 0; h < H; h++) red[(tid >> 6) * H + h] = mx[h];
    }
    __syncthreads();
    #pragma unroll
    for (int h = 0; h < H; h++) mx[h] = fmaxf(red[h], red[H + h]);
    __syncthreads();
  }

  // ---- pass B: per-head sum of exp(e - m) ----
  float sm[H];
  #pragma unroll
  for (int h = 0; h < H; h++) sm[h] = 0.f;
  for (int i = start + tid; i < end; i += NT){
    int src = csr_src[i];
    if constexpr (H == 4){
      float4 a4 = *reinterpret_cast<const float4*>(&al[(size_t)src * 4]);
      float ev[4] = {a4.x + arv[0], a4.y + arv[1], a4.z + arv[2], a4.w + arv[3]};
      #pragma unroll
      for (int h = 0; h < 4; h++){ float e = ev[h]; e = e > 0.f ? e : 0.2f * e; sm[h] += __expf(e - mx[h]); }
    } else {
      float e = al[src] + arv[0]; e = e > 0.f ? e : 0.2f * e; sm[0] += __expf(e - mx[0]);
    }
  }
  #pragma unroll
  for (int h = 0; h < H; h++){
    #pragma unroll
    for (int off = 32; off; off >>= 1) sm[h] += __shfl_xor(sm[h], off);
  }
  if constexpr (NW > 1){
    if ((tid & 63) == 0){
      #pragma unroll
      for (int h = 0; h < H; h++) red[(tid >> 6) * H + h] = sm[h];
    }
    __syncthreads();
    #pragma unroll
    for (int h = 0; h < H; h++) sm[h] = red[h] + red[H + h];
  }
  if (tid == 0){
    #pragma unroll
    for (int h = 0; h < H; h++){ sh_m[h] = mx[h]; sh_is[h] = 1.f / (sm[h] + 1e-16f); }
  }
  __syncthreads();

  // ---- chunked alpha (once per edge per head, in LDS) + aggregate ----
  const int h_me = (2 * tid) / C;
  float acc0 = 0.f, acc1 = 0.f;

  for (int c0 = start; c0 < end; c0 += 64){
    const int cnt = min(64, end - c0);
    __syncthreads();   // previous chunk fully consumed
    #pragma unroll
    for (int idx = tid; idx < 64 * H; idx += NT){
      int eo = idx & 63, h = idx >> 6;
      if (eo < cnt){
        int src = csr_src[c0 + eo];
        if (h == 0) sh_src[eo] = src;
        float e = al[(size_t)src * H + h] + sh_ar[h];
        e = e > 0.f ? e : 0.2f * e;
        sh_alpha[h][eo] = __expf(e - sh_m[h]) * sh_is[h];
      }
    }
    __syncthreads();
    for (int j = 0; j < cnt; j++){
      int src = sh_src[j];
      float a = sh_alpha[h_me][j];
      uint pv = *reinterpret_cast<const uint*>(&xl[(size_t)src * DIM + 2 * tid]);
      acc0 = fmaf(a, bf2f((ushort)(pv & 0xffffu)), acc0);
      acc1 = fmaf(a, bf2f((ushort)(pv >> 16)), acc1);
    }
  }

  // ---- bias + LayerNorm + ReLU ----
  float2 bb = *reinterpret_cast<const float2*>(&bias[2 * tid]);
  float v0 = acc0 + bb.x, v1 = acc1 + bb.y;
  float s1 = v0 + v1, s2 = v0 * v0 + v1 * v1;
  #pragma unroll
  for (int off = 32; off; off >>= 1){ s1 += __shfl_xor(s1, off); s2 += __shfl_xor(s2, off); }
  if ((tid & 63) == 0){ r1[tid >> 6] = s1; r2[tid >> 6] = s2; }
  __syncthreads();
  if (tid == 0){
    float S1 = 0.f, S2 = 0.f;
    #pragma unroll
    for (int w = 0; w < NW; w++){ S1 += r1[w]; S2 += r2[w]; }
    float mu = S1 / DIM;
    float var = S2 / DIM - mu * mu;
    rmu = mu;
    rstd = rsqrtf(var + EPS_LN);
  }
  __syncthreads();
  float2 gg = *reinterpret_cast<const float2*>(&gamma[2 * tid]);
  float2 be = *reinterpret_cast<const float2*>(&beta[2 * tid]);
  float2 o;
  o.x = fmaxf((v0 - rmu) * rstd * gg.x + be.x, 0.f);
  o.y = fmaxf((v1 - rmu) * rstd * gg.y + be.y, 0.f);
  *reinterpret_cast<float2*>(&out[(size_t)n * DIM + 2 * tid]) = o;
}

// ---------------- pooling ----------------
__global__ void k_count(const int* __restrict__ batch, int* __restrict__ cnt, int N){
  int i = blockIdx.x * 256 + threadIdx.x;
  if (i < N) atomicAdd(&cnt[batch[i]], 1);
}

__global__ __launch_bounds__(128) void k_pool(const float* __restrict__ h, const int* __restrict__ batch,
    float* __restrict__ pool_sum, unsigned* __restrict__ pool_max, int N){
  const int c = (int)threadIdx.x;  // 0..127
  int n0 = blockIdx.x * 64;
  if (n0 >= N) return;
  int n1 = min(n0 + 64, N);
  float s = 0.f, mx = 0.f;           // post-ReLU values are >= 0
  int cur = batch[n0];
  for (int n = n0; n < n1; n++){
    int b = batch[n];
    if (b != cur){
      atomicAdd(&pool_sum[cur * 128 + c], s);
      atomicMax(&pool_max[cur * 128 + c], __float_as_uint(mx));
      s = 0.f; mx = 0.f; cur = b;
    }
    float v = h[(size_t)n * 128 + c];
    s += v; mx = fmaxf(mx, v);
  }
  atomicAdd(&pool_sum[cur * 128 + c], s);
  atomicMax(&pool_max[cur * 128 + c], __float_as_uint(mx));
}

__global__ __launch_bounds__(128) void k_final(const float* __restrict__ pool_sum,
    const unsigned* __restrict__ pool_max, const int* __restrict__ cnt,
    const float* __restrict__ Wp, const float* __restrict__ bp, float* __restrict__ out){
  const int g = blockIdx.x;
  const int j = (int)threadIdx.x;
  float inv = 1.f / fmaxf((float)cnt[g], 1.f);
  float acc = bp[j];
  #pragma unroll 4
  for (int k = 0; k < 128; k++)
    acc = fmaf(pool_sum[g * 128 + k] * inv, Wp[k * 128 + j], acc);
  #pragma unroll 4
  for (int k = 0; k < 128; k++)
    acc = fmaf(__uint_as_float(pool_max[g * 128 + k]), Wp[(128 + k) * 128 + j], acc);
  out[g * 128 + j] = acc;
}

// ---------------- launch ----------------
extern "C" void kernel_launch(void* const* d_in, const int* in_sizes, int n_in,
                              void* d_out, int out_size, void* d_ws, size_t ws_size,
                              hipStream_t stream){
  const float* x     = (const float*)d_in[0];
  const int*   ei    = (const int*)d_in[1];
  const int*   batch = (const int*)d_in[2];
  const float* W1    = (const float*)d_in[3];
  const float* asrc1 = (const float*)d_in[4];
  const float* adst1 = (const float*)d_in[5];
  const float* b1    = (const float*)d_in[6];
  const float* g1    = (const float*)d_in[7];
  const float* be1   = (const float*)d_in[8];
  const float* W2    = (const float*)d_in[9];
  const float* asrc2 = (const float*)d_in[10];
  const float* adst2 = (const float*)d_in[11];
  const float* b2    = (const float*)d_in[12];
  const float* g2    = (const float*)d_in[13];
  const float* be2   = (const float*)d_in[14];
  const float* W3    = (const float*)d_in[15];
  const float* asrc3 = (const float*)d_in[16];
  const float* adst3 = (const float*)d_in[17];
  const float* b3    = (const float*)d_in[18];
  const float* g3    = (const float*)d_in[19];
  const float* be3   = (const float*)d_in[20];
  const float* Wp    = (const float*)d_in[21];
  const float* bp    = (const float*)d_in[22];

  const int N = in_sizes[0] / 128;
  const int E = in_sizes[1] / 2;
  const int G = out_size / 128;
  const int EN = E + N;

  char* ws = (char*)d_ws;
  size_t off = 0;
  auto alloc = [&](size_t bytes) -> char* {
    char* p = ws + off;
    off = (off + bytes + 255) & ~(size_t)255;
    return p;
  };
  ushort*   xbufA    = (ushort*)alloc((size_t)N * 256 * 2);  // xl (bf16)
  float*    xbufB    = (float*)alloc((size_t)N * 256 * 4);   // layer output h (f32)
  float*    al       = (float*)alloc((size_t)N * 4 * 4);
  float*    ar       = (float*)alloc((size_t)N * 4 * 4);
  int*      deg      = (int*)alloc((size_t)N * 4);
  int*      row_ptr  = (int*)alloc((size_t)(N + 1) * 4);
  int*      cursor   = (int*)alloc((size_t)N * 4);
  int*      csr_src  = (int*)alloc((size_t)EN * 4);
  int*      cnt      = (int*)alloc((size_t)G * 4);
  float*    pool_sum = (float*)alloc((size_t)G * 128 * 4);
  unsigned* pool_max = (unsigned*)alloc((size_t)G * 128 * 4);

  hipMemsetAsync(deg, 0, (size_t)N * 4, stream);
  hipMemsetAsync(cnt, 0, (size_t)G * 4, stream);
  hipMemsetAsync(pool_sum, 0, (size_t)G * 128 * 4, stream);
  hipMemsetAsync(pool_max, 0, (size_t)G * 128 * 4, stream);

  // CSR build (shared by all 3 layers)
  k_deg<<<(EN + 255) / 256, 256, 0, stream>>>(ei, deg, E, N);
  k_scan<<<1, 1024, 0, stream>>>(deg, row_ptr, cursor, N);
  k_scatter<<<(EN + 255) / 256, 256, 0, stream>>>(ei, cursor, csr_src, E, N);

  // Layer 1: 128 -> 256, H=4, C=64
  k_gemm<128, 256><<<(N + 15) / 16, 256, 0, stream>>>(x, W1, xbufA, N);
  k_coef<4, 256><<<(N + 3) / 4, 256, 0, stream>>>(xbufA, asrc1, adst1, al, ar, N);
  k_agg2<4, 256><<<N, 128, 0, stream>>>(xbufA, al, ar, row_ptr, csr_src, b1, g1, be1, xbufB);

  // Layer 2: 256 -> 256, H=4, C=64
  k_gemm<256, 256><<<(N + 15) / 16, 256, 0, stream>>>(xbufB, W2, xbufA, N);
  k_coef<4, 256><<<(N + 3) / 4, 256, 0, stream>>>(xbufA, asrc2, adst2, al, ar, N);
  k_agg2<4, 256><<<N, 128, 0, stream>>>(xbufA, al, ar, row_ptr, csr_src, b2, g2, be2, xbufB);

  // Layer 3: 256 -> 128, H=1, C=128
  k_gemm<256, 128><<<(N + 15) / 16, 256, 0, stream>>>(xbufB, W3, xbufA, N);
  k_coef<1, 128><<<(N + 3) / 4, 256, 0, stream>>>(xbufA, asrc3, adst3, al, ar, N);
  k_agg2<1, 128><<<N, 64, 0, stream>>>(xbufA, al, ar, row_ptr, csr_src, b3, g3, be3, xbufB);

  // Pooling + final projection
  k_count<<<(N + 255) / 256, 256, 0, stream>>>(batch, cnt, N);
  k_pool<<<(N + 63) / 64, 128, 0, stream>>>(xbufB, batch, pool_sum, pool_max, N);
  k_final<<<G, 128, 0, stream>>>(pool_sum, pool_max, cnt, Wp, bp, (float*)d_out);
}

// Round 4
// 836.320 us; speedup vs baseline: 1.9681x; 1.2373x over previous
//
#include <hip/hip_runtime.h>

#define EPS_LN 1e-5f
typedef unsigned int uint;

__device__ inline float bf2f(ushort h){ return __uint_as_float(((uint)h) << 16); }
__device__ inline ushort f2bf(float f){
  uint u = __float_as_uint(f);
  u += 0x7fffu + ((u >> 16) & 1u);   // round-to-nearest-even
  return (ushort)(u >> 16);
}

// ---------------- CSR build (dst-indexed) ----------------
__global__ void k_deg(const int* __restrict__ ei, int* __restrict__ deg, int E, int N){
  int e = blockIdx.x * 256 + threadIdx.x;
  if (e >= E + N) return;
  int dst = (e < E) ? ei[E + e] : (e - E);   // self loops appended
  atomicAdd(&deg[dst], 1);
}

__global__ __launch_bounds__(1024) void k_scan(const int* __restrict__ deg, int* __restrict__ row_ptr,
                                               int* __restrict__ cursor, int n){
  __shared__ int lds[1024];
  __shared__ int carry;
  if (threadIdx.x == 0){ carry = 0; row_ptr[0] = 0; }
  __syncthreads();
  for (int base = 0; base < n; base += 1024){
    int i = base + (int)threadIdx.x;
    int v = (i < n) ? deg[i] : 0;
    lds[threadIdx.x] = v;
    __syncthreads();
    for (int off = 1; off < 1024; off <<= 1){
      int t = (threadIdx.x >= (unsigned)off) ? lds[threadIdx.x - off] : 0;
      __syncthreads();
      lds[threadIdx.x] += t;
      __syncthreads();
    }
    int inc = lds[threadIdx.x] + carry;
    if (i < n){ row_ptr[i + 1] = inc; cursor[i] = inc - v; }
    __syncthreads();
    if (threadIdx.x == 1023) carry = inc;
    __syncthreads();
  }
}

__global__ void k_scatter(const int* __restrict__ ei, int* __restrict__ cursor,
                          int* __restrict__ csr_src, int E, int N){
  int e = blockIdx.x * 256 + threadIdx.x;
  if (e >= E + N) return;
  int src, dst;
  if (e < E){ src = ei[e]; dst = ei[E + e]; } else { src = dst = e - E; }
  int pos = atomicAdd(&cursor[dst], 1);
  csr_src[pos] = src;
}

// ---------------- graph segment bounds via binary search (batch is sorted) ----------------
__global__ void k_bounds(const int* __restrict__ batch, int* __restrict__ pos, int N, int G){
  int g = (int)threadIdx.x;
  if (g > G) return;
  int lo = 0, hi = N;             // first i with batch[i] >= g
  while (lo < hi){
    int mid = (lo + hi) >> 1;
    if (batch[mid] < g) lo = mid + 1; else hi = mid;
  }
  pos[g] = lo;
}

// ---------------- GEMM: out[N,OUT](bf16) = A[N,K](f32) @ W[K,OUT](f32) ----------------
template<int K, int OUT>
__global__ __launch_bounds__(256) void k_gemm(const float* __restrict__ A, const float* __restrict__ W,
                                              ushort* __restrict__ out, int N)
{
  constexpr int ROWS = 16;
  constexpr int CG = OUT / 4;        // col groups (4 cols per thread)
  constexpr int RG = 256 / CG;       // row groups
  constexpr int RP = ROWS / RG;      // rows per thread
  __shared__ float At[K][ROWS + 1];
  const int row0 = blockIdx.x * ROWS;
  const int tid = (int)threadIdx.x;

  for (int idx = tid; idx < ROWS * K; idx += 256){
    int r = idx / K;
    int k = idx - r * K;
    int row = row0 + r;
    At[k][r] = (row < N) ? A[(size_t)row * K + k] : 0.f;
  }
  __syncthreads();

  const int cg = tid % CG;
  const int rg = tid / CG;
  float acc[RP][4];
  #pragma unroll
  for (int r = 0; r < RP; r++){ acc[r][0] = acc[r][1] = acc[r][2] = acc[r][3] = 0.f; }

  const float* Wb = W + cg * 4;
  #pragma unroll 4
  for (int k = 0; k < K; k++){
    const float4 w = *reinterpret_cast<const float4*>(Wb + (size_t)k * OUT);
    #pragma unroll
    for (int r = 0; r < RP; r++){
      float a = At[k][rg * RP + r];
      acc[r][0] = fmaf(a, w.x, acc[r][0]);
      acc[r][1] = fmaf(a, w.y, acc[r][1]);
      acc[r][2] = fmaf(a, w.z, acc[r][2]);
      acc[r][3] = fmaf(a, w.w, acc[r][3]);
    }
  }
  #pragma unroll
  for (int r = 0; r < RP; r++){
    int row = row0 + rg * RP + r;
    if (row < N){
      ushort4 v;
      v.x = f2bf(acc[r][0]); v.y = f2bf(acc[r][1]);
      v.z = f2bf(acc[r][2]); v.w = f2bf(acc[r][3]);
      *reinterpret_cast<ushort4*>(&out[(size_t)row * OUT + cg * 4]) = v;
    }
  }
}

// ---------------- attention coefficients from bf16 xl ----------------
template<int H, int DIM>
__global__ __launch_bounds__(256) void k_coef(const ushort* __restrict__ xl,
    const float* __restrict__ asrc, const float* __restrict__ adst,
    float* __restrict__ al, float* __restrict__ ar, int N)
{
  constexpr int EPL = DIM / 64;       // elems per lane (4 or 2)
  constexpr int C = DIM / H;
  constexpr int LG = C / EPL;         // lanes per head group
  const int lane = (int)threadIdx.x & 63;
  const int n = blockIdx.x * 4 + ((int)threadIdx.x >> 6);
  if (n >= N) return;
  const size_t base = (size_t)n * DIM + lane * EPL;
  ushort xv[EPL];
  if constexpr (EPL == 4){ *reinterpret_cast<uint2*>(xv) = *reinterpret_cast<const uint2*>(&xl[base]); }
  else                   { *reinterpret_cast<uint*>(xv)  = *reinterpret_cast<const uint*>(&xl[base]); }
  float pa = 0.f, pb = 0.f;
  #pragma unroll
  for (int j = 0; j < EPL; j++){
    float x = bf2f(xv[j]);
    pa = fmaf(x, asrc[lane * EPL + j], pa);
    pb = fmaf(x, adst[lane * EPL + j], pb);
  }
  #pragma unroll
  for (int off = 1; off < LG; off <<= 1){ pa += __shfl_xor(pa, off); pb += __shfl_xor(pb, off); }
  if ((lane & (LG - 1)) == 0){
    int h = lane / LG;
    al[(size_t)n * H + h] = pa;
    ar[(size_t)n * H + h] = pb;
  }
}

// ---------------- per-node gather: softmax + aggregate + bias + LN + ReLU ----------------
// NT = DIM/2 threads; each thread owns 2 output columns.
template<int H, int DIM>
__global__ __launch_bounds__(DIM / 2) void k_agg2(
    const ushort* __restrict__ xl,
    const float* __restrict__ al, const float* __restrict__ ar,
    const int* __restrict__ row_ptr, const int* __restrict__ csr_src,
    const float* __restrict__ bias, const float* __restrict__ gamma, const float* __restrict__ beta,
    float* __restrict__ out)
{
  constexpr int NT = DIM / 2;
  constexpr int NW = NT / 64;
  constexpr int C = DIM / H;
  const int n = blockIdx.x;
  const int tid = (int)threadIdx.x;
  const int start = row_ptr[n], end = row_ptr[n + 1];

  __shared__ int   sh_src[64];
  __shared__ float sh_alpha[H][64];
  __shared__ float sh_m[H], sh_is[H], sh_ar[H];
  __shared__ float red[(NW > 1 ? NW : 1) * H];
  __shared__ float r1[NW], r2[NW];
  __shared__ float rmu, rstd;

  if (tid < H) sh_ar[tid] = ar[(size_t)n * H + tid];

  float arv[H];
  #pragma unroll
  for (int h = 0; h < H; h++) arv[h] = ar[(size_t)n * H + h];

  // ---- pass A: per-head max of leaky(e) ----
  float mx[H];
  #pragma unroll
  for (int h = 0; h < H; h++) mx[h] = -1e30f;
  for (int i = start + tid; i < end; i += NT){
    int src = csr_src[i];
    if constexpr (H == 4){
      float4 a4 = *reinterpret_cast<const float4*>(&al[(size_t)src * 4]);
      float ev[4] = {a4.x + arv[0], a4.y + arv[1], a4.z + arv[2], a4.w + arv[3]};
      #pragma unroll
      for (int h = 0; h < 4; h++){ float e = ev[h]; e = e > 0.f ? e : 0.2f * e; mx[h] = fmaxf(mx[h], e); }
    } else {
      float e = al[src] + arv[0]; e = e > 0.f ? e : 0.2f * e; mx[0] = fmaxf(mx[0], e);
    }
  }
  #pragma unroll
  for (int h = 0; h < H; h++){
    #pragma unroll
    for (int off = 32; off; off >>= 1) mx[h] = fmaxf(mx[h], __shfl_xor(mx[h], off));
  }
  if constexpr (NW > 1){
    if ((tid & 63) == 0){
      #pragma unroll
      for (int h = 0; h < H; h++) red[(tid >> 6) * H + h] = mx[h];
    }
    __syncthreads();
    #pragma unroll
    for (int h = 0; h < H; h++) mx[h] = fmaxf(red[h], red[H + h]);
    __syncthreads();
  }

  // ---- pass B: per-head sum of exp(e - m) ----
  float sm[H];
  #pragma unroll
  for (int h = 0; h < H; h++) sm[h] = 0.f;
  for (int i = start + tid; i < end; i += NT){
    int src = csr_src[i];
    if constexpr (H == 4){
      float4 a4 = *reinterpret_cast<const float4*>(&al[(size_t)src * 4]);
      float ev[4] = {a4.x + arv[0], a4.y + arv[1], a4.z + arv[2], a4.w + arv[3]};
      #pragma unroll
      for (int h = 0; h < 4; h++){ float e = ev[h]; e = e > 0.f ? e : 0.2f * e; sm[h] += __expf(e - mx[h]); }
    } else {
      float e = al[src] + arv[0]; e = e > 0.f ? e : 0.2f * e; sm[0] += __expf(e - mx[0]);
    }
  }
  #pragma unroll
  for (int h = 0; h < H; h++){
    #pragma unroll
    for (int off = 32; off; off >>= 1) sm[h] += __shfl_xor(sm[h], off);
  }
  if constexpr (NW > 1){
    if ((tid & 63) == 0){
      #pragma unroll
      for (int h = 0; h < H; h++) red[(tid >> 6) * H + h] = sm[h];
    }
    __syncthreads();
    #pragma unroll
    for (int h = 0; h < H; h++) sm[h] = red[h] + red[H + h];
  }
  if (tid == 0){
    #pragma unroll
    for (int h = 0; h < H; h++){ sh_m[h] = mx[h]; sh_is[h] = 1.f / (sm[h] + 1e-16f); }
  }
  __syncthreads();

  // ---- chunked alpha (once per edge per head, in LDS) + aggregate ----
  const int h_me = (2 * tid) / C;
  float acc0 = 0.f, acc1 = 0.f;

  for (int c0 = start; c0 < end; c0 += 64){
    const int cnt = min(64, end - c0);
    __syncthreads();   // previous chunk fully consumed
    #pragma unroll
    for (int idx = tid; idx < 64 * H; idx += NT){
      int eo = idx & 63, h = idx >> 6;
      if (eo < cnt){
        int src = csr_src[c0 + eo];
        if (h == 0) sh_src[eo] = src;
        float e = al[(size_t)src * H + h] + sh_ar[h];
        e = e > 0.f ? e : 0.2f * e;
        sh_alpha[h][eo] = __expf(e - sh_m[h]) * sh_is[h];
      }
    }
    __syncthreads();
    for (int j = 0; j < cnt; j++){
      int src = sh_src[j];
      float a = sh_alpha[h_me][j];
      uint pv = *reinterpret_cast<const uint*>(&xl[(size_t)src * DIM + 2 * tid]);
      acc0 = fmaf(a, bf2f((ushort)(pv & 0xffffu)), acc0);
      acc1 = fmaf(a, bf2f((ushort)(pv >> 16)), acc1);
    }
  }

  // ---- bias + LayerNorm + ReLU ----
  float2 bb = *reinterpret_cast<const float2*>(&bias[2 * tid]);
  float v0 = acc0 + bb.x, v1 = acc1 + bb.y;
  float s1 = v0 + v1, s2 = v0 * v0 + v1 * v1;
  #pragma unroll
  for (int off = 32; off; off >>= 1){ s1 += __shfl_xor(s1, off); s2 += __shfl_xor(s2, off); }
  if ((tid & 63) == 0){ r1[tid >> 6] = s1; r2[tid >> 6] = s2; }
  __syncthreads();
  if (tid == 0){
    float S1 = 0.f, S2 = 0.f;
    #pragma unroll
    for (int w = 0; w < NW; w++){ S1 += r1[w]; S2 += r2[w]; }
    float mu = S1 / DIM;
    float var = S2 / DIM - mu * mu;
    rmu = mu;
    rstd = rsqrtf(var + EPS_LN);
  }
  __syncthreads();
  float2 gg = *reinterpret_cast<const float2*>(&gamma[2 * tid]);
  float2 be = *reinterpret_cast<const float2*>(&beta[2 * tid]);
  float2 o;
  o.x = fmaxf((v0 - rmu) * rstd * gg.x + be.x, 0.f);
  o.y = fmaxf((v1 - rmu) * rstd * gg.y + be.y, 0.f);
  *reinterpret_cast<float2*>(&out[(size_t)n * DIM + 2 * tid]) = o;
}

// ---------------- pooling over pos ranges (4 chunks per graph, one flush per block) ----------------
__global__ __launch_bounds__(128) void k_pool(const float* __restrict__ h, const int* __restrict__ pos,
    float* __restrict__ pool_sum, unsigned* __restrict__ pool_max){
  const int c = (int)threadIdx.x;           // channel 0..127
  const int g = blockIdx.x >> 2;            // graph
  const int q = blockIdx.x & 3;             // quarter
  const int s = pos[g], e = pos[g + 1];
  const int len = e - s;
  if (len <= 0) return;
  const int chunk = (len + 3) >> 2;
  const int n0 = s + q * chunk;
  const int n1 = min(n0 + chunk, e);
  if (n0 >= n1) return;
  float sum = 0.f, mx = 0.f;                // post-ReLU values >= 0
  for (int n = n0; n < n1; n++){
    float v = h[(size_t)n * 128 + c];
    sum += v; mx = fmaxf(mx, v);
  }
  atomicAdd(&pool_sum[g * 128 + c], sum);
  atomicMax(&pool_max[g * 128 + c], __float_as_uint(mx));
}

__global__ __launch_bounds__(128) void k_final(const float* __restrict__ pool_sum,
    const unsigned* __restrict__ pool_max, const int* __restrict__ pos,
    const float* __restrict__ Wp, const float* __restrict__ bp, float* __restrict__ out){
  const int g = blockIdx.x;
  const int j = (int)threadIdx.x;
  float inv = 1.f / fmaxf((float)(pos[g + 1] - pos[g]), 1.f);
  float acc = bp[j];
  #pragma unroll 4
  for (int k = 0; k < 128; k++)
    acc = fmaf(pool_sum[g * 128 + k] * inv, Wp[k * 128 + j], acc);
  #pragma unroll 4
  for (int k = 0; k < 128; k++)
    acc = fmaf(__uint_as_float(pool_max[g * 128 + k]), Wp[(128 + k) * 128 + j], acc);
  out[g * 128 + j] = acc;
}

// ---------------- launch ----------------
extern "C" void kernel_launch(void* const* d_in, const int* in_sizes, int n_in,
                              void* d_out, int out_size, void* d_ws, size_t ws_size,
                              hipStream_t stream){
  const float* x     = (const float*)d_in[0];
  const int*   ei    = (const int*)d_in[1];
  const int*   batch = (const int*)d_in[2];
  const float* W1    = (const float*)d_in[3];
  const float* asrc1 = (const float*)d_in[4];
  const float* adst1 = (const float*)d_in[5];
  const float* b1    = (const float*)d_in[6];
  const float* g1    = (const float*)d_in[7];
  const float* be1   = (const float*)d_in[8];
  const float* W2    = (const float*)d_in[9];
  const float* asrc2 = (const float*)d_in[10];
  const float* adst2 = (const float*)d_in[11];
  const float* b2    = (const float*)d_in[12];
  const float* g2    = (const float*)d_in[13];
  const float* be2   = (const float*)d_in[14];
  const float* W3    = (const float*)d_in[15];
  const float* asrc3 = (const float*)d_in[16];
  const float* adst3 = (const float*)d_in[17];
  const float* b3    = (const float*)d_in[18];
  const float* g3    = (const float*)d_in[19];
  const float* be3   = (const float*)d_in[20];
  const float* Wp    = (const float*)d_in[21];
  const float* bp    = (const float*)d_in[22];

  const int N = in_sizes[0] / 128;
  const int E = in_sizes[1] / 2;
  const int G = out_size / 128;
  const int EN = E + N;

  char* ws = (char*)d_ws;
  size_t off = 0;
  auto alloc = [&](size_t bytes) -> char* {
    char* p = ws + off;
    off = (off + bytes + 255) & ~(size_t)255;
    return p;
  };
  ushort*   xbufA    = (ushort*)alloc((size_t)N * 256 * 2);  // xl (bf16)
  float*    xbufB    = (float*)alloc((size_t)N * 256 * 4);   // layer output h (f32)
  float*    al       = (float*)alloc((size_t)N * 4 * 4);
  float*    ar       = (float*)alloc((size_t)N * 4 * 4);
  int*      deg      = (int*)alloc((size_t)N * 4);
  int*      row_ptr  = (int*)alloc((size_t)(N + 1) * 4);
  int*      cursor   = (int*)alloc((size_t)N * 4);
  int*      csr_src  = (int*)alloc((size_t)EN * 4);
  int*      pos      = (int*)alloc((size_t)(G + 1) * 4);
  float*    pool_sum = (float*)alloc((size_t)G * 128 * 4);
  unsigned* pool_max = (unsigned*)alloc((size_t)G * 128 * 4);

  hipMemsetAsync(deg, 0, (size_t)N * 4, stream);
  hipMemsetAsync(pool_sum, 0, (size_t)G * 128 * 4, stream);
  hipMemsetAsync(pool_max, 0, (size_t)G * 128 * 4, stream);

  // CSR build (shared by all 3 layers) + graph bounds
  k_deg<<<(EN + 255) / 256, 256, 0, stream>>>(ei, deg, E, N);
  k_scan<<<1, 1024, 0, stream>>>(deg, row_ptr, cursor, N);
  k_scatter<<<(EN + 255) / 256, 256, 0, stream>>>(ei, cursor, csr_src, E, N);
  k_bounds<<<1, 128, 0, stream>>>(batch, pos, N, G);

  // Layer 1: 128 -> 256, H=4, C=64
  k_gemm<128, 256><<<(N + 15) / 16, 256, 0, stream>>>(x, W1, xbufA, N);
  k_coef<4, 256><<<(N + 3) / 4, 256, 0, stream>>>(xbufA, asrc1, adst1, al, ar, N);
  k_agg2<4, 256><<<N, 128, 0, stream>>>(xbufA, al, ar, row_ptr, csr_src, b1, g1, be1, xbufB);

  // Layer 2: 256 -> 256, H=4, C=64
  k_gemm<256, 256><<<(N + 15) / 16, 256, 0, stream>>>(xbufB, W2, xbufA, N);
  k_coef<4, 256><<<(N + 3) / 4, 256, 0, stream>>>(xbufA, asrc2, adst2, al, ar, N);
  k_agg2<4, 256><<<N, 128, 0, stream>>>(xbufA, al, ar, row_ptr, csr_src, b2, g2, be2, xbufB);

  // Layer 3: 256 -> 128, H=1, C=128
  k_gemm<256, 128><<<(N + 15) / 16, 256, 0, stream>>>(xbufB, W3, xbufA, N);
  k_coef<1, 128><<<(N + 3) / 4, 256, 0, stream>>>(xbufA, asrc3, adst3, al, ar, N);
  k_agg2<1, 128><<<N, 64, 0, stream>>>(xbufA, al, ar, row_ptr, csr_src, b3, g3, be3, xbufB);

  // Pooling + final projection
  k_pool<<<G * 4, 128, 0, stream>>>(xbufB, pos, pool_sum, pool_max);
  k_final<<<G, 128, 0, stream>>>(pool_sum, pool_max, pos, Wp, bp, (float*)d_out);
}

// Round 5
// 652.763 us; speedup vs baseline: 2.5216x; 1.2812x over previous
//
#include <hip/hip_runtime.h>

#define EPS_LN 1e-5f
typedef unsigned int uint;

using bf16x8 = __attribute__((ext_vector_type(8))) short;
using f32x4  = __attribute__((ext_vector_type(4))) float;

__device__ inline float bf2f(ushort h){ return __uint_as_float(((uint)h) << 16); }
__device__ inline ushort f2bf(float f){
  uint u = __float_as_uint(f);
  u += 0x7fffu + ((u >> 16) & 1u);   // round-to-nearest-even
  return (ushort)(u >> 16);
}

// ---------------- CSR build (dst-indexed) ----------------
__global__ void k_deg(const int* __restrict__ ei, int* __restrict__ deg, int E, int N){
  int e = blockIdx.x * 256 + threadIdx.x;
  if (e >= E + N) return;
  int dst = (e < E) ? ei[E + e] : (e - E);   // self loops appended
  atomicAdd(&deg[dst], 1);
}

__global__ __launch_bounds__(1024) void k_scan(const int* __restrict__ deg, int* __restrict__ row_ptr,
                                               int* __restrict__ cursor, int n){
  __shared__ int lds[1024];
  __shared__ int carry;
  if (threadIdx.x == 0){ carry = 0; row_ptr[0] = 0; }
  __syncthreads();
  for (int base = 0; base < n; base += 1024){
    int i = base + (int)threadIdx.x;
    int v = (i < n) ? deg[i] : 0;
    lds[threadIdx.x] = v;
    __syncthreads();
    for (int off = 1; off < 1024; off <<= 1){
      int t = (threadIdx.x >= (unsigned)off) ? lds[threadIdx.x - off] : 0;
      __syncthreads();
      lds[threadIdx.x] += t;
      __syncthreads();
    }
    int inc = lds[threadIdx.x] + carry;
    if (i < n){ row_ptr[i + 1] = inc; cursor[i] = inc - v; }
    __syncthreads();
    if (threadIdx.x == 1023) carry = inc;
    __syncthreads();
  }
}

__global__ void k_scatter(const int* __restrict__ ei, int* __restrict__ cursor,
                          int* __restrict__ csr_src, int E, int N){
  int e = blockIdx.x * 256 + threadIdx.x;
  if (e >= E + N) return;
  int src, dst;
  if (e < E){ src = ei[e]; dst = ei[E + e]; } else { src = dst = e - E; }
  int pos = atomicAdd(&cursor[dst], 1);
  csr_src[pos] = src;
}

// ---------------- graph segment bounds via binary search (batch is sorted) ----------------
__global__ void k_bounds(const int* __restrict__ batch, int* __restrict__ pos, int N, int G){
  int g = (int)threadIdx.x;
  if (g > G) return;
  int lo = 0, hi = N;             // first i with batch[i] >= g
  while (lo < hi){
    int mid = (lo + hi) >> 1;
    if (batch[mid] < g) lo = mid + 1; else hi = mid;
  }
  pos[g] = lo;
}

// ---------------- dtype prep ----------------
__global__ void k_cast(const float* __restrict__ in, ushort* __restrict__ out, int n4){
  int i = blockIdx.x * 256 + threadIdx.x;
  if (i >= n4) return;
  float4 v = reinterpret_cast<const float4*>(in)[i];
  ushort4 o;
  o.x = f2bf(v.x); o.y = f2bf(v.y); o.z = f2bf(v.z); o.w = f2bf(v.w);
  reinterpret_cast<ushort4*>(out)[i] = o;
}

// Wt[n][k] (bf16) = W[k][n] (f32)
__global__ void k_wt(const float* __restrict__ W, ushort* __restrict__ Wt, int K, int N){
  int idx = blockIdx.x * 256 + threadIdx.x;
  if (idx >= K * N) return;
  int n = idx / K, k = idx - n * K;
  Wt[idx] = f2bf(W[(size_t)k * N + n]);
}

// ---------------- MFMA GEMM: out[M,N](bf16) = A[M,K](bf16) @ W[K,N], W given as Wt[N,K](bf16) ----
// 128x128 block tile, 4 waves each 64x64 (4x4 of 16x16x32 MFMA), BK=128, XOR-swizzled LDS.
template<int K, int N>
__global__ __launch_bounds__(256, 2) void k_mm(const ushort* __restrict__ A,
                                               const ushort* __restrict__ Wt,
                                               ushort* __restrict__ out, int M)
{
  __shared__ __align__(16) ushort ldsA[128 * 128];
  __shared__ __align__(16) ushort ldsB[128 * 128];

  const int t = (int)threadIdx.x;
  const int lane = t & 63;
  const int w = t >> 6;
  const int wm = w >> 1, wn = w & 1;
  const int row0 = blockIdx.x * 128;
  const int n0 = blockIdx.y * 128;
  const int trow = t >> 4;     // 0..15
  const int tk = t & 15;       // kb8 index

  f32x4 acc[4][4];
  #pragma unroll
  for (int mt = 0; mt < 4; mt++)
    #pragma unroll
    for (int nt = 0; nt < 4; nt++)
      acc[mt][nt] = (f32x4){0.f, 0.f, 0.f, 0.f};

  #pragma unroll
  for (int kt = 0; kt < K / 128; kt++){
    uint4 ra[8], rb[8];
    #pragma unroll
    for (int p = 0; p < 8; p++){
      int arow = p * 16 + trow;
      int grow = row0 + arow; if (grow > M - 1) grow = M - 1;
      ra[p] = *reinterpret_cast<const uint4*>(&A[(size_t)grow * K + kt * 128 + tk * 8]);
      rb[p] = *reinterpret_cast<const uint4*>(&Wt[(size_t)(n0 + arow) * K + kt * 128 + tk * 8]);
    }
    if (kt) __syncthreads();          // previous tile fully consumed
    #pragma unroll
    for (int p = 0; p < 8; p++){
      int arow = p * 16 + trow;
      int sw = (tk ^ (arow & 7)) * 8;
      *reinterpret_cast<uint4*>(&ldsA[arow * 128 + sw]) = ra[p];
      *reinterpret_cast<uint4*>(&ldsB[arow * 128 + sw]) = rb[p];
    }
    __syncthreads();

    #pragma unroll
    for (int ks = 0; ks < 4; ks++){
      bf16x8 af[4], bfr[4];
      const int kb8 = ks * 4 + (lane >> 4);
      #pragma unroll
      for (int mt = 0; mt < 4; mt++){
        int arow = wm * 64 + mt * 16 + (lane & 15);
        af[mt] = *reinterpret_cast<const bf16x8*>(&ldsA[arow * 128 + ((kb8 ^ (arow & 7)) * 8)]);
        int brow = wn * 64 + mt * 16 + (lane & 15);
        bfr[mt] = *reinterpret_cast<const bf16x8*>(&ldsB[brow * 128 + ((kb8 ^ (brow & 7)) * 8)]);
      }
      #pragma unroll
      for (int mt = 0; mt < 4; mt++)
        #pragma unroll
        for (int nt = 0; nt < 4; nt++)
          acc[mt][nt] = __builtin_amdgcn_mfma_f32_16x16x32_bf16(af[mt], bfr[nt], acc[mt][nt], 0, 0, 0);
    }
  }

  // epilogue: C/D map col=lane&15, row=(lane>>4)*4+r  (m89-verified)
  #pragma unroll
  for (int mt = 0; mt < 4; mt++){
    const int grow_b = row0 + wm * 64 + mt * 16 + (lane >> 4) * 4;
    #pragma unroll
    for (int nt = 0; nt < 4; nt++){
      const int gcol = n0 + wn * 64 + nt * 16 + (lane & 15);
      #pragma unroll
      for (int r = 0; r < 4; r++){
        int grow = grow_b + r;
        if (grow < M) out[(size_t)grow * N + gcol] = f2bf(acc[mt][nt][r]);
      }
    }
  }
}

// ---------------- attention coefficients from bf16 xl ----------------
template<int H, int DIM>
__global__ __launch_bounds__(256) void k_coef(const ushort* __restrict__ xl,
    const float* __restrict__ asrc, const float* __restrict__ adst,
    float* __restrict__ al, float* __restrict__ ar, int N)
{
  constexpr int EPL = DIM / 64;       // elems per lane (4 or 2)
  constexpr int C = DIM / H;
  constexpr int LG = C / EPL;         // lanes per head group
  const int lane = (int)threadIdx.x & 63;
  const int n = blockIdx.x * 4 + ((int)threadIdx.x >> 6);
  if (n >= N) return;
  const size_t base = (size_t)n * DIM + lane * EPL;
  ushort xv[EPL];
  if constexpr (EPL == 4){ *reinterpret_cast<uint2*>(xv) = *reinterpret_cast<const uint2*>(&xl[base]); }
  else                   { *reinterpret_cast<uint*>(xv)  = *reinterpret_cast<const uint*>(&xl[base]); }
  float pa = 0.f, pb = 0.f;
  #pragma unroll
  for (int j = 0; j < EPL; j++){
    float x = bf2f(xv[j]);
    pa = fmaf(x, asrc[lane * EPL + j], pa);
    pb = fmaf(x, adst[lane * EPL + j], pb);
  }
  #pragma unroll
  for (int off = 1; off < LG; off <<= 1){ pa += __shfl_xor(pa, off); pb += __shfl_xor(pb, off); }
  if ((lane & (LG - 1)) == 0){
    int h = lane / LG;
    al[(size_t)n * H + h] = pa;
    ar[(size_t)n * H + h] = pb;
  }
}

// ---------------- per-node gather: softmax + aggregate + bias + LN + ReLU ----------------
// NT = DIM/2 threads; each thread owns 2 output columns. BF16_OUT: write packed bf16 (for next GEMM).
template<int H, int DIM, bool BF16_OUT>
__global__ __launch_bounds__(DIM / 2) void k_agg2(
    const ushort* __restrict__ xl,
    const float* __restrict__ al, const float* __restrict__ ar,
    const int* __restrict__ row_ptr, const int* __restrict__ csr_src,
    const float* __restrict__ bias, const float* __restrict__ gamma, const float* __restrict__ beta,
    float* __restrict__ out)
{
  constexpr int NT = DIM / 2;
  constexpr int NW = NT / 64;
  constexpr int C = DIM / H;
  const int n = blockIdx.x;
  const int tid = (int)threadIdx.x;
  const int start = row_ptr[n], end = row_ptr[n + 1];

  __shared__ int   sh_src[64];
  __shared__ float sh_alpha[H][64];
  __shared__ float sh_m[H], sh_is[H], sh_ar[H];
  __shared__ float red[(NW > 1 ? NW : 1) * H];
  __shared__ float r1[NW], r2[NW];
  __shared__ float rmu, rstd;

  if (tid < H) sh_ar[tid] = ar[(size_t)n * H + tid];

  float arv[H];
  #pragma unroll
  for (int h = 0; h < H; h++) arv[h] = ar[(size_t)n * H + h];

  // ---- pass A: per-head max of leaky(e) ----
  float mx[H];
  #pragma unroll
  for (int h = 0; h < H; h++) mx[h] = -1e30f;
  for (int i = start + tid; i < end; i += NT){
    int src = csr_src[i];
    if constexpr (H == 4){
      float4 a4 = *reinterpret_cast<const float4*>(&al[(size_t)src * 4]);
      float ev[4] = {a4.x + arv[0], a4.y + arv[1], a4.z + arv[2], a4.w + arv[3]};
      #pragma unroll
      for (int h = 0; h < 4; h++){ float e = ev[h]; e = e > 0.f ? e : 0.2f * e; mx[h] = fmaxf(mx[h], e); }
    } else {
      float e = al[src] + arv[0]; e = e > 0.f ? e : 0.2f * e; mx[0] = fmaxf(mx[0], e);
    }
  }
  #pragma unroll
  for (int h = 0; h < H; h++){
    #pragma unroll
    for (int off = 32; off; off >>= 1) mx[h] = fmaxf(mx[h], __shfl_xor(mx[h], off));
  }
  if constexpr (NW > 1){
    if ((tid & 63) == 0){
      #pragma unroll
      for (int h = 0; h < H; h++) red[(tid >> 6) * H + h] = mx[h];
    }
    __syncthreads();
    #pragma unroll
    for (int h = 0; h < H; h++) mx[h] = fmaxf(red[h], red[H + h]);
    __syncthreads();
  }

  // ---- pass B: per-head sum of exp(e - m) ----
  float sm[H];
  #pragma unroll
  for (int h = 0; h < H; h++) sm[h] = 0.f;
  for (int i = start + tid; i < end; i += NT){
    int src = csr_src[i];
    if constexpr (H == 4){
      float4 a4 = *reinterpret_cast<const float4*>(&al[(size_t)src * 4]);
      float ev[4] = {a4.x + arv[0], a4.y + arv[1], a4.z + arv[2], a4.w + arv[3]};
      #pragma unroll
      for (int h = 0; h < 4; h++){ float e = ev[h]; e = e > 0.f ? e : 0.2f * e; sm[h] += __expf(e - mx[h]); }
    } else {
      float e = al[src] + arv[0]; e = e > 0.f ? e : 0.2f * e; sm[0] += __expf(e - mx[0]);
    }
  }
  #pragma unroll
  for (int h = 0; h < H; h++){
    #pragma unroll
    for (int off = 32; off; off >>= 1) sm[h] += __shfl_xor(sm[h], off);
  }
  if constexpr (NW > 1){
    if ((tid & 63) == 0){
      #pragma unroll
      for (int h = 0; h < H; h++) red[(tid >> 6) * H + h] = sm[h];
    }
    __syncthreads();
    #pragma unroll
    for (int h = 0; h < H; h++) sm[h] = red[h] + red[H + h];
  }
  if (tid == 0){
    #pragma unroll
    for (int h = 0; h < H; h++){ sh_m[h] = mx[h]; sh_is[h] = 1.f / (sm[h] + 1e-16f); }
  }
  __syncthreads();

  // ---- chunked alpha (once per edge per head, in LDS) + aggregate ----
  const int h_me = (2 * tid) / C;
  float acc0 = 0.f, acc1 = 0.f;

  for (int c0 = start; c0 < end; c0 += 64){
    const int cnt = min(64, end - c0);
    __syncthreads();   // previous chunk fully consumed
    #pragma unroll
    for (int idx = tid; idx < 64 * H; idx += NT){
      int eo = idx & 63, h = idx >> 6;
      if (eo < cnt){
        int src = csr_src[c0 + eo];
        if (h == 0) sh_src[eo] = src;
        float e = al[(size_t)src * H + h] + sh_ar[h];
        e = e > 0.f ? e : 0.2f * e;
        sh_alpha[h][eo] = __expf(e - sh_m[h]) * sh_is[h];
      }
    }
    __syncthreads();
    for (int j = 0; j < cnt; j++){
      int src = sh_src[j];
      float a = sh_alpha[h_me][j];
      uint pv = *reinterpret_cast<const uint*>(&xl[(size_t)src * DIM + 2 * tid]);
      acc0 = fmaf(a, bf2f((ushort)(pv & 0xffffu)), acc0);
      acc1 = fmaf(a, bf2f((ushort)(pv >> 16)), acc1);
    }
  }

  // ---- bias + LayerNorm + ReLU ----
  float2 bb = *reinterpret_cast<const float2*>(&bias[2 * tid]);
  float v0 = acc0 + bb.x, v1 = acc1 + bb.y;
  float s1 = v0 + v1, s2 = v0 * v0 + v1 * v1;
  #pragma unroll
  for (int off = 32; off; off >>= 1){ s1 += __shfl_xor(s1, off); s2 += __shfl_xor(s2, off); }
  if ((tid & 63) == 0){ r1[tid >> 6] = s1; r2[tid >> 6] = s2; }
  __syncthreads();
  if (tid == 0){
    float S1 = 0.f, S2 = 0.f;
    #pragma unroll
    for (int w = 0; w < NW; w++){ S1 += r1[w]; S2 += r2[w]; }
    float mu = S1 / DIM;
    float var = S2 / DIM - mu * mu;
    rmu = mu;
    rstd = rsqrtf(var + EPS_LN);
  }
  __syncthreads();
  float2 gg = *reinterpret_cast<const float2*>(&gamma[2 * tid]);
  float2 be = *reinterpret_cast<const float2*>(&beta[2 * tid]);
  float o0 = fmaxf((v0 - rmu) * rstd * gg.x + be.x, 0.f);
  float o1 = fmaxf((v1 - rmu) * rstd * gg.y + be.y, 0.f);
  if constexpr (BF16_OUT){
    uint pk = (uint)f2bf(o0) | ((uint)f2bf(o1) << 16);
    reinterpret_cast<uint*>(out)[(size_t)n * (DIM / 2) + tid] = pk;
  } else {
    *reinterpret_cast<float2*>(&out[(size_t)n * DIM + 2 * tid]) = make_float2(o0, o1);
  }
}

// ---------------- pooling over pos ranges ----------------
__global__ __launch_bounds__(128) void k_pool(const float* __restrict__ h, const int* __restrict__ pos,
    float* __restrict__ pool_sum, unsigned* __restrict__ pool_max){
  const int c = (int)threadIdx.x;           // channel 0..127
  const int g = blockIdx.x >> 2;            // graph
  const int q = blockIdx.x & 3;             // quarter
  const int s = pos[g], e = pos[g + 1];
  const int len = e - s;
  if (len <= 0) return;
  const int chunk = (len + 3) >> 2;
  const int n0 = s + q * chunk;
  const int n1 = min(n0 + chunk, e);
  if (n0 >= n1) return;
  float sum = 0.f, mx = 0.f;                // post-ReLU values >= 0
  for (int n = n0; n < n1; n++){
    float v = h[(size_t)n * 128 + c];
    sum += v; mx = fmaxf(mx, v);
  }
  atomicAdd(&pool_sum[g * 128 + c], sum);
  atomicMax(&pool_max[g * 128 + c], __float_as_uint(mx));
}

__global__ __launch_bounds__(128) void k_final(const float* __restrict__ pool_sum,
    const unsigned* __restrict__ pool_max, const int* __restrict__ pos,
    const float* __restrict__ Wp, const float* __restrict__ bp, float* __restrict__ out){
  const int g = blockIdx.x;
  const int j = (int)threadIdx.x;
  float inv = 1.f / fmaxf((float)(pos[g + 1] - pos[g]), 1.f);
  float acc = bp[j];
  #pragma unroll 4
  for (int k = 0; k < 128; k++)
    acc = fmaf(pool_sum[g * 128 + k] * inv, Wp[k * 128 + j], acc);
  #pragma unroll 4
  for (int k = 0; k < 128; k++)
    acc = fmaf(__uint_as_float(pool_max[g * 128 + k]), Wp[(128 + k) * 128 + j], acc);
  out[g * 128 + j] = acc;
}

// ---------------- launch ----------------
extern "C" void kernel_launch(void* const* d_in, const int* in_sizes, int n_in,
                              void* d_out, int out_size, void* d_ws, size_t ws_size,
                              hipStream_t stream){
  const float* x     = (const float*)d_in[0];
  const int*   ei    = (const int*)d_in[1];
  const int*   batch = (const int*)d_in[2];
  const float* W1    = (const float*)d_in[3];
  const float* asrc1 = (const float*)d_in[4];
  const float* adst1 = (const float*)d_in[5];
  const float* b1    = (const float*)d_in[6];
  const float* g1    = (const float*)d_in[7];
  const float* be1   = (const float*)d_in[8];
  const float* W2    = (const float*)d_in[9];
  const float* asrc2 = (const float*)d_in[10];
  const float* adst2 = (const float*)d_in[11];
  const float* b2    = (const float*)d_in[12];
  const float* g2    = (const float*)d_in[13];
  const float* be2   = (const float*)d_in[14];
  const float* W3    = (const float*)d_in[15];
  const float* asrc3 = (const float*)d_in[16];
  const float* adst3 = (const float*)d_in[17];
  const float* b3    = (const float*)d_in[18];
  const float* g3    = (const float*)d_in[19];
  const float* be3   = (const float*)d_in[20];
  const float* Wp    = (const float*)d_in[21];
  const float* bp    = (const float*)d_in[22];

  const int N = in_sizes[0] / 128;
  const int E = in_sizes[1] / 2;
  const int G = out_size / 128;
  const int EN = E + N;

  char* ws = (char*)d_ws;
  size_t off = 0;
  auto alloc = [&](size_t bytes) -> char* {
    char* p = ws + off;
    off = (off + bytes + 255) & ~(size_t)255;
    return p;
  };
  // region0: x_bf (N*128 bf16) lives here until agg2-L1 overwrites it with h_bf (N*256 bf16)
  ushort*   region0  = (ushort*)alloc((size_t)N * 256 * 2);
  ushort*   x_bf     = region0;
  ushort*   h_bf     = region0;
  ushort*   xbufA    = (ushort*)alloc((size_t)N * 256 * 2);  // xl (bf16)
  float*    xbufB    = (float*)alloc((size_t)N * 128 * 4);   // layer-3 output (f32, for pooling)
  float*    al       = (float*)alloc((size_t)N * 4 * 4);
  float*    ar       = (float*)alloc((size_t)N * 4 * 4);
  int*      deg      = (int*)alloc((size_t)N * 4);
  int*      row_ptr  = (int*)alloc((size_t)(N + 1) * 4);
  int*      cursor   = (int*)alloc((size_t)N * 4);
  int*      csr_src  = (int*)alloc((size_t)EN * 4);
  int*      pos      = (int*)alloc((size_t)(G + 1) * 4);
  float*    pool_sum = (float*)alloc((size_t)G * 128 * 4);
  unsigned* pool_max = (unsigned*)alloc((size_t)G * 128 * 4);
  ushort*   W1t      = (ushort*)alloc((size_t)256 * 128 * 2);  // [N=256][K=128]
  ushort*   W2t      = (ushort*)alloc((size_t)256 * 256 * 2);  // [256][256]
  ushort*   W3t      = (ushort*)alloc((size_t)128 * 256 * 2);  // [128][256]

  hipMemsetAsync(deg, 0, (size_t)N * 4, stream);
  hipMemsetAsync(pool_sum, 0, (size_t)G * 128 * 4, stream);
  hipMemsetAsync(pool_max, 0, (size_t)G * 128 * 4, stream);

  // CSR build + graph bounds + dtype prep
  k_deg<<<(EN + 255) / 256, 256, 0, stream>>>(ei, deg, E, N);
  k_scan<<<1, 1024, 0, stream>>>(deg, row_ptr, cursor, N);
  k_scatter<<<(EN + 255) / 256, 256, 0, stream>>>(ei, cursor, csr_src, E, N);
  k_bounds<<<1, 128, 0, stream>>>(batch, pos, N, G);
  k_cast<<<(N * 128 / 4 + 255) / 256, 256, 0, stream>>>(x, x_bf, N * 128 / 4);
  k_wt<<<(128 * 256 + 255) / 256, 256, 0, stream>>>(W1, W1t, 128, 256);
  k_wt<<<(256 * 256 + 255) / 256, 256, 0, stream>>>(W2, W2t, 256, 256);
  k_wt<<<(256 * 128 + 255) / 256, 256, 0, stream>>>(W3, W3t, 256, 128);

  const int MB = (N + 127) / 128;

  // Layer 1: 128 -> 256, H=4, C=64
  k_mm<128, 256><<<dim3(MB, 2), 256, 0, stream>>>(x_bf, W1t, xbufA, N);
  k_coef<4, 256><<<(N + 3) / 4, 256, 0, stream>>>(xbufA, asrc1, adst1, al, ar, N);
  k_agg2<4, 256, true><<<N, 128, 0, stream>>>(xbufA, al, ar, row_ptr, csr_src, b1, g1, be1, (float*)h_bf);

  // Layer 2: 256 -> 256, H=4, C=64
  k_mm<256, 256><<<dim3(MB, 2), 256, 0, stream>>>(h_bf, W2t, xbufA, N);
  k_coef<4, 256><<<(N + 3) / 4, 256, 0, stream>>>(xbufA, asrc2, adst2, al, ar, N);
  k_agg2<4, 256, true><<<N, 128, 0, stream>>>(xbufA, al, ar, row_ptr, csr_src, b2, g2, be2, (float*)h_bf);

  // Layer 3: 256 -> 128, H=1, C=128
  k_mm<256, 128><<<dim3(MB, 1), 256, 0, stream>>>(h_bf, W3t, xbufA, N);
  k_coef<1, 128><<<(N + 3) / 4, 256, 0, stream>>>(xbufA, asrc3, adst3, al, ar, N);
  k_agg2<1, 128, false><<<N, 64, 0, stream>>>(xbufA, al, ar, row_ptr, csr_src, b3, g3, be3, xbufB);

  // Pooling + final projection
  k_pool<<<G * 4, 128, 0, stream>>>(xbufB, pos, pool_sum, pool_max);
  k_final<<<G, 128, 0, stream>>>(pool_sum, pool_max, pos, Wp, bp, (float*)d_out);
}

// Round 6
// 580.870 us; speedup vs baseline: 2.8337x; 1.1238x over previous
//
#include <hip/hip_runtime.h>

#define EPS_LN 1e-5f
typedef unsigned int uint;

using bf16x8 = __attribute__((ext_vector_type(8))) short;
using f32x4  = __attribute__((ext_vector_type(4))) float;

__device__ inline float bf2f(ushort h){ return __uint_as_float(((uint)h) << 16); }
__device__ inline ushort f2bf(float f){
  uint u = __float_as_uint(f);
  u += 0x7fffu + ((u >> 16) & 1u);   // round-to-nearest-even
  return (ushort)(u >> 16);
}

// ---------------- CSR build (dst-indexed) ----------------
__global__ void k_deg(const int* __restrict__ ei, int* __restrict__ deg, int E, int N){
  int e = blockIdx.x * 256 + threadIdx.x;
  if (e >= E + N) return;
  int dst = (e < E) ? ei[E + e] : (e - E);   // self loops appended
  atomicAdd(&deg[dst], 1);
}

// shuffle-based single-block scan (few barriers)
__global__ __launch_bounds__(1024) void k_scan(const int* __restrict__ deg, int* __restrict__ row_ptr,
                                               int* __restrict__ cursor, int n){
  __shared__ int wsum[16];
  __shared__ int carry_s;
  const int t = (int)threadIdx.x, lane = t & 63, w = t >> 6;
  if (t == 0){ carry_s = 0; row_ptr[0] = 0; }
  __syncthreads();
  for (int base = 0; base < n; base += 1024){
    int i = base + t;
    int v = (i < n) ? deg[i] : 0;
    int s = v;
    #pragma unroll
    for (int off = 1; off < 64; off <<= 1){
      int u = __shfl_up(s, off);
      if (lane >= off) s += u;
    }
    if (lane == 63) wsum[w] = s;
    __syncthreads();
    if (w == 0 && lane < 16){
      int sc = wsum[lane];
      #pragma unroll
      for (int off = 1; off < 16; off <<= 1){
        int u = __shfl_up(sc, off);
        if (lane >= off) sc += u;
      }
      wsum[lane] = sc;
    }
    __syncthreads();
    int carry = carry_s;
    int prefix = carry + (w ? wsum[w - 1] : 0) + s;     // inclusive
    if (i < n){ row_ptr[i + 1] = prefix; cursor[i] = prefix - v; }
    __syncthreads();
    if (t == 1023) carry_s = prefix;
    __syncthreads();
  }
}

__global__ void k_scatter(const int* __restrict__ ei, int* __restrict__ cursor,
                          int* __restrict__ csr_src, int E, int N){
  int e = blockIdx.x * 256 + threadIdx.x;
  if (e >= E + N) return;
  int src, dst;
  if (e < E){ src = ei[e]; dst = ei[E + e]; } else { src = dst = e - E; }
  int pos = atomicAdd(&cursor[dst], 1);
  csr_src[pos] = src;
}

// ---------------- graph segment bounds via binary search (batch is sorted) ----------------
__global__ void k_bounds(const int* __restrict__ batch, int* __restrict__ pos, int N, int G){
  int g = (int)threadIdx.x;
  if (g > G) return;
  int lo = 0, hi = N;             // first i with batch[i] >= g
  while (lo < hi){
    int mid = (lo + hi) >> 1;
    if (batch[mid] < g) lo = mid + 1; else hi = mid;
  }
  pos[g] = lo;
}

// ---------------- dtype prep ----------------
__global__ void k_cast(const float* __restrict__ in, ushort* __restrict__ out, int n4){
  int i = blockIdx.x * 256 + threadIdx.x;
  if (i >= n4) return;
  float4 v = reinterpret_cast<const float4*>(in)[i];
  ushort4 o;
  o.x = f2bf(v.x); o.y = f2bf(v.y); o.z = f2bf(v.z); o.w = f2bf(v.w);
  reinterpret_cast<ushort4*>(out)[i] = o;
}

// Wt[n][k] (bf16) = W[k][n] (f32)
__global__ void k_wt(const float* __restrict__ W, ushort* __restrict__ Wt, int K, int N){
  int idx = blockIdx.x * 256 + threadIdx.x;
  if (idx >= K * N) return;
  int n = idx / K, k = idx - n * K;
  Wt[idx] = f2bf(W[(size_t)k * N + n]);
}

// ---------------- MFMA GEMM: out[M,N](bf16) = A[M,K](bf16) @ W[K,N], W given as Wt[N,K](bf16) ----
template<int K, int N>
__global__ __launch_bounds__(256, 2) void k_mm(const ushort* __restrict__ A,
                                               const ushort* __restrict__ Wt,
                                               ushort* __restrict__ out, int M)
{
  __shared__ __align__(16) ushort ldsA[128 * 128];
  __shared__ __align__(16) ushort ldsB[128 * 128];

  const int t = (int)threadIdx.x;
  const int lane = t & 63;
  const int w = t >> 6;
  const int wm = w >> 1, wn = w & 1;
  const int row0 = blockIdx.x * 128;
  const int n0 = blockIdx.y * 128;
  const int trow = t >> 4;     // 0..15
  const int tk = t & 15;       // kb8 index

  f32x4 acc[4][4];
  #pragma unroll
  for (int mt = 0; mt < 4; mt++)
    #pragma unroll
    for (int nt = 0; nt < 4; nt++)
      acc[mt][nt] = (f32x4){0.f, 0.f, 0.f, 0.f};

  #pragma unroll
  for (int kt = 0; kt < K / 128; kt++){
    uint4 ra[8], rb[8];
    #pragma unroll
    for (int p = 0; p < 8; p++){
      int arow = p * 16 + trow;
      int grow = row0 + arow; if (grow > M - 1) grow = M - 1;
      ra[p] = *reinterpret_cast<const uint4*>(&A[(size_t)grow * K + kt * 128 + tk * 8]);
      rb[p] = *reinterpret_cast<const uint4*>(&Wt[(size_t)(n0 + arow) * K + kt * 128 + tk * 8]);
    }
    if (kt) __syncthreads();          // previous tile fully consumed
    #pragma unroll
    for (int p = 0; p < 8; p++){
      int arow = p * 16 + trow;
      int sw = (tk ^ (arow & 7)) * 8;
      *reinterpret_cast<uint4*>(&ldsA[arow * 128 + sw]) = ra[p];
      *reinterpret_cast<uint4*>(&ldsB[arow * 128 + sw]) = rb[p];
    }
    __syncthreads();

    #pragma unroll
    for (int ks = 0; ks < 4; ks++){
      bf16x8 af[4], bfr[4];
      const int kb8 = ks * 4 + (lane >> 4);
      #pragma unroll
      for (int mt = 0; mt < 4; mt++){
        int arow = wm * 64 + mt * 16 + (lane & 15);
        af[mt] = *reinterpret_cast<const bf16x8*>(&ldsA[arow * 128 + ((kb8 ^ (arow & 7)) * 8)]);
        int brow = wn * 64 + mt * 16 + (lane & 15);
        bfr[mt] = *reinterpret_cast<const bf16x8*>(&ldsB[brow * 128 + ((kb8 ^ (brow & 7)) * 8)]);
      }
      #pragma unroll
      for (int mt = 0; mt < 4; mt++)
        #pragma unroll
        for (int nt = 0; nt < 4; nt++)
          acc[mt][nt] = __builtin_amdgcn_mfma_f32_16x16x32_bf16(af[mt], bfr[nt], acc[mt][nt], 0, 0, 0);
    }
  }

  // epilogue: C/D map col=lane&15, row=(lane>>4)*4+r  (m89-verified)
  #pragma unroll
  for (int mt = 0; mt < 4; mt++){
    const int grow_b = row0 + wm * 64 + mt * 16 + (lane >> 4) * 4;
    #pragma unroll
    for (int nt = 0; nt < 4; nt++){
      const int gcol = n0 + wn * 64 + nt * 16 + (lane & 15);
      #pragma unroll
      for (int r = 0; r < 4; r++){
        int grow = grow_b + r;
        if (grow < M) out[(size_t)grow * N + gcol] = f2bf(acc[mt][nt][r]);
      }
    }
  }
}

// ---------------- attention coefficients from bf16 xl ----------------
template<int H, int DIM>
__global__ __launch_bounds__(256) void k_coef(const ushort* __restrict__ xl,
    const float* __restrict__ asrc, const float* __restrict__ adst,
    float* __restrict__ al, float* __restrict__ ar, int N)
{
  constexpr int EPL = DIM / 64;       // elems per lane (4 or 2)
  constexpr int C = DIM / H;
  constexpr int LG = C / EPL;         // lanes per head group
  const int lane = (int)threadIdx.x & 63;
  const int n = blockIdx.x * 4 + ((int)threadIdx.x >> 6);
  if (n >= N) return;
  const size_t base = (size_t)n * DIM + lane * EPL;
  ushort xv[EPL];
  if constexpr (EPL == 4){ *reinterpret_cast<uint2*>(xv) = *reinterpret_cast<const uint2*>(&xl[base]); }
  else                   { *reinterpret_cast<uint*>(xv)  = *reinterpret_cast<const uint*>(&xl[base]); }
  float pa = 0.f, pb = 0.f;
  #pragma unroll
  for (int j = 0; j < EPL; j++){
    float x = bf2f(xv[j]);
    pa = fmaf(x, asrc[lane * EPL + j], pa);
    pb = fmaf(x, adst[lane * EPL + j], pb);
  }
  #pragma unroll
  for (int off = 1; off < LG; off <<= 1){ pa += __shfl_xor(pa, off); pb += __shfl_xor(pb, off); }
  if ((lane & (LG - 1)) == 0){
    int h = lane / LG;
    al[(size_t)n * H + h] = pa;
    ar[(size_t)n * H + h] = pb;
  }
}

// ---------------- per-node wave gather: softmax + aggregate + bias + LN + ReLU ----------------
// One WAVE per node (4 waves/block, independent). No block barriers.
template<int H, int DIM, bool BF16_OUT>
__global__ __launch_bounds__(256) void k_aggw(
    const ushort* __restrict__ xl,
    const float* __restrict__ al, const float* __restrict__ ar,
    const int* __restrict__ row_ptr, const int* __restrict__ csr_src,
    const float* __restrict__ bias, const float* __restrict__ gamma, const float* __restrict__ beta,
    float* __restrict__ out, int N)
{
  constexpr int EPL = DIM / 64;        // cols per lane: 4 (DIM=256) or 2 (DIM=128)
  constexpr int SLOT = H + 1;          // per-edge LDS floats: byte-offset + H p-values
  const int tid = (int)threadIdx.x;
  const int wid = tid >> 6, lane = tid & 63;
  __shared__ float plds_all[4][64 * SLOT];
  float* plds = plds_all[wid];
  const int n = blockIdx.x * 4 + wid;
  if (n >= N) return;
  const int start = row_ptr[n], end = row_ptr[n + 1];

  float arv[H];
  #pragma unroll
  for (int h = 0; h < H; h++) arv[h] = ar[(size_t)n * H + h];

  // ---- pass A: per-head max of leaky(al[src]+ar[n]) ----
  float mx[H];
  #pragma unroll
  for (int h = 0; h < H; h++) mx[h] = -1e30f;
  for (int i = start + lane; i < end; i += 64){
    int src = csr_src[i];
    if constexpr (H == 4){
      float4 a4 = *reinterpret_cast<const float4*>(&al[(size_t)src * 4]);
      float e0 = a4.x + arv[0]; e0 = e0 > 0.f ? e0 : 0.2f * e0; mx[0] = fmaxf(mx[0], e0);
      float e1 = a4.y + arv[1]; e1 = e1 > 0.f ? e1 : 0.2f * e1; mx[1] = fmaxf(mx[1], e1);
      float e2 = a4.z + arv[2]; e2 = e2 > 0.f ? e2 : 0.2f * e2; mx[2] = fmaxf(mx[2], e2);
      float e3 = a4.w + arv[3]; e3 = e3 > 0.f ? e3 : 0.2f * e3; mx[3] = fmaxf(mx[3], e3);
    } else {
      float e = al[src] + arv[0]; e = e > 0.f ? e : 0.2f * e; mx[0] = fmaxf(mx[0], e);
    }
  }
  #pragma unroll
  for (int h = 0; h < H; h++){
    #pragma unroll
    for (int off = 32; off; off >>= 1) mx[h] = fmaxf(mx[h], __shfl_xor(mx[h], off));
  }

  const int hm = (H == 4) ? (lane >> 4) : 0;   // my head (C=64: 4 cols per lane within one head)
  float acc[EPL];
  #pragma unroll
  for (int e = 0; e < EPL; e++) acc[e] = 0.f;
  float psum[H];
  #pragma unroll
  for (int h = 0; h < H; h++) psum[h] = 0.f;
  const char* xlb = (const char*)xl;

  // ---- chunked: fill p + offset into wave-local LDS, then gather-accumulate ----
  for (int c0 = start; c0 < end; c0 += 64){
    const int cnt = min(64, end - c0);
    __asm__ volatile("s_waitcnt lgkmcnt(0)" ::: "memory");   // prev chunk reads drained
    __builtin_amdgcn_wave_barrier();
    if (lane < cnt){
      int src = csr_src[c0 + lane];
      plds[lane * SLOT] = __uint_as_float((uint)src * (uint)(DIM * 2));
      if constexpr (H == 4){
        float4 a4 = *reinterpret_cast<const float4*>(&al[(size_t)src * 4]);
        float e0 = a4.x + arv[0]; e0 = e0 > 0.f ? e0 : 0.2f * e0; float p0 = __expf(e0 - mx[0]);
        float e1 = a4.y + arv[1]; e1 = e1 > 0.f ? e1 : 0.2f * e1; float p1 = __expf(e1 - mx[1]);
        float e2 = a4.z + arv[2]; e2 = e2 > 0.f ? e2 : 0.2f * e2; float p2 = __expf(e2 - mx[2]);
        float e3 = a4.w + arv[3]; e3 = e3 > 0.f ? e3 : 0.2f * e3; float p3 = __expf(e3 - mx[3]);
        plds[lane * SLOT + 1] = p0; plds[lane * SLOT + 2] = p1;
        plds[lane * SLOT + 3] = p2; plds[lane * SLOT + 4] = p3;
        psum[0] += p0; psum[1] += p1; psum[2] += p2; psum[3] += p3;
      } else {
        float e = al[src] + arv[0]; e = e > 0.f ? e : 0.2f * e; float p = __expf(e - mx[0]);
        plds[lane * SLOT + 1] = p; psum[0] += p;
      }
    }
    __asm__ volatile("s_waitcnt lgkmcnt(0)" ::: "memory");   // fills visible wave-wide
    __builtin_amdgcn_wave_barrier();
    #pragma unroll 2
    for (int j = 0; j < cnt; j++){
      uint off = __builtin_amdgcn_readfirstlane(__float_as_uint(plds[j * SLOT]));
      float p = plds[j * SLOT + 1 + hm];
      if constexpr (EPL == 4){
        uint2 pv = *reinterpret_cast<const uint2*>(xlb + off + lane * 8);
        acc[0] = fmaf(p, __uint_as_float(pv.x << 16), acc[0]);
        acc[1] = fmaf(p, __uint_as_float(pv.x & 0xffff0000u), acc[1]);
        acc[2] = fmaf(p, __uint_as_float(pv.y << 16), acc[2]);
        acc[3] = fmaf(p, __uint_as_float(pv.y & 0xffff0000u), acc[3]);
      } else {
        uint pv = *reinterpret_cast<const uint*>(xlb + off + lane * 4);
        acc[0] = fmaf(p, __uint_as_float(pv << 16), acc[0]);
        acc[1] = fmaf(p, __uint_as_float(pv & 0xffff0000u), acc[1]);
      }
    }
  }

  // ---- normalize: s = wave-sum of p, once ----
  #pragma unroll
  for (int h = 0; h < H; h++){
    #pragma unroll
    for (int off = 32; off; off >>= 1) psum[h] += __shfl_xor(psum[h], off);
  }
  float ssel;
  if constexpr (H == 4){
    ssel = (hm == 0) ? psum[0] : (hm == 1) ? psum[1] : (hm == 2) ? psum[2] : psum[3];
  } else {
    ssel = psum[0];
  }
  const float inv = 1.f / (ssel + 1e-16f);

  // ---- bias + LayerNorm + ReLU (all-shuffle, no LDS) ----
  float v[EPL];
  if constexpr (EPL == 4){
    float4 bb = *reinterpret_cast<const float4*>(&bias[lane * 4]);
    v[0] = fmaf(acc[0], inv, bb.x); v[1] = fmaf(acc[1], inv, bb.y);
    v[2] = fmaf(acc[2], inv, bb.z); v[3] = fmaf(acc[3], inv, bb.w);
  } else {
    float2 bb = *reinterpret_cast<const float2*>(&bias[lane * 2]);
    v[0] = fmaf(acc[0], inv, bb.x); v[1] = fmaf(acc[1], inv, bb.y);
  }
  float s1 = 0.f, s2 = 0.f;
  #pragma unroll
  for (int e = 0; e < EPL; e++){ s1 += v[e]; s2 += v[e] * v[e]; }
  #pragma unroll
  for (int off = 32; off; off >>= 1){ s1 += __shfl_xor(s1, off); s2 += __shfl_xor(s2, off); }
  const float mu = s1 / DIM;
  const float rstd = rsqrtf(s2 / DIM - mu * mu + EPS_LN);

  if constexpr (EPL == 4){
    float4 gg = *reinterpret_cast<const float4*>(&gamma[lane * 4]);
    float4 be = *reinterpret_cast<const float4*>(&beta[lane * 4]);
    float o0 = fmaxf((v[0] - mu) * rstd * gg.x + be.x, 0.f);
    float o1 = fmaxf((v[1] - mu) * rstd * gg.y + be.y, 0.f);
    float o2 = fmaxf((v[2] - mu) * rstd * gg.z + be.z, 0.f);
    float o3 = fmaxf((v[3] - mu) * rstd * gg.w + be.w, 0.f);
    if constexpr (BF16_OUT){
      uint2 pk;
      pk.x = (uint)f2bf(o0) | ((uint)f2bf(o1) << 16);
      pk.y = (uint)f2bf(o2) | ((uint)f2bf(o3) << 16);
      *reinterpret_cast<uint2*>(&reinterpret_cast<ushort*>(out)[(size_t)n * DIM + lane * 4]) = pk;
    } else {
      *reinterpret_cast<float4*>(&out[(size_t)n * DIM + lane * 4]) = make_float4(o0, o1, o2, o3);
    }
  } else {
    float2 gg = *reinterpret_cast<const float2*>(&gamma[lane * 2]);
    float2 be = *reinterpret_cast<const float2*>(&beta[lane * 2]);
    float o0 = fmaxf((v[0] - mu) * rstd * gg.x + be.x, 0.f);
    float o1 = fmaxf((v[1] - mu) * rstd * gg.y + be.y, 0.f);
    if constexpr (BF16_OUT){
      uint pk = (uint)f2bf(o0) | ((uint)f2bf(o1) << 16);
      reinterpret_cast<uint*>(out)[(size_t)n * (DIM / 2) + lane] = pk;
    } else {
      *reinterpret_cast<float2*>(&out[(size_t)n * DIM + lane * 2]) = make_float2(o0, o1);
    }
  }
}

// ---------------- pooling over pos ranges ----------------
__global__ __launch_bounds__(128) void k_pool(const float* __restrict__ h, const int* __restrict__ pos,
    float* __restrict__ pool_sum, unsigned* __restrict__ pool_max){
  const int c = (int)threadIdx.x;           // channel 0..127
  const int g = blockIdx.x >> 2;            // graph
  const int q = blockIdx.x & 3;             // quarter
  const int s = pos[g], e = pos[g + 1];
  const int len = e - s;
  if (len <= 0) return;
  const int chunk = (len + 3) >> 2;
  const int n0 = s + q * chunk;
  const int n1 = min(n0 + chunk, e);
  if (n0 >= n1) return;
  float sum = 0.f, mx = 0.f;                // post-ReLU values >= 0
  for (int n = n0; n < n1; n++){
    float v = h[(size_t)n * 128 + c];
    sum += v; mx = fmaxf(mx, v);
  }
  atomicAdd(&pool_sum[g * 128 + c], sum);
  atomicMax(&pool_max[g * 128 + c], __float_as_uint(mx));
}

__global__ __launch_bounds__(128) void k_final(const float* __restrict__ pool_sum,
    const unsigned* __restrict__ pool_max, const int* __restrict__ pos,
    const float* __restrict__ Wp, const float* __restrict__ bp, float* __restrict__ out){
  const int g = blockIdx.x;
  const int j = (int)threadIdx.x;
  float inv = 1.f / fmaxf((float)(pos[g + 1] - pos[g]), 1.f);
  float acc = bp[j];
  #pragma unroll 4
  for (int k = 0; k < 128; k++)
    acc = fmaf(pool_sum[g * 128 + k] * inv, Wp[k * 128 + j], acc);
  #pragma unroll 4
  for (int k = 0; k < 128; k++)
    acc = fmaf(__uint_as_float(pool_max[g * 128 + k]), Wp[(128 + k) * 128 + j], acc);
  out[g * 128 + j] = acc;
}

// ---------------- launch ----------------
extern "C" void kernel_launch(void* const* d_in, const int* in_sizes, int n_in,
                              void* d_out, int out_size, void* d_ws, size_t ws_size,
                              hipStream_t stream){
  const float* x     = (const float*)d_in[0];
  const int*   ei    = (const int*)d_in[1];
  const int*   batch = (const int*)d_in[2];
  const float* W1    = (const float*)d_in[3];
  const float* asrc1 = (const float*)d_in[4];
  const float* adst1 = (const float*)d_in[5];
  const float* b1    = (const float*)d_in[6];
  const float* g1    = (const float*)d_in[7];
  const float* be1   = (const float*)d_in[8];
  const float* W2    = (const float*)d_in[9];
  const float* asrc2 = (const float*)d_in[10];
  const float* adst2 = (const float*)d_in[11];
  const float* b2    = (const float*)d_in[12];
  const float* g2    = (const float*)d_in[13];
  const float* be2   = (const float*)d_in[14];
  const float* W3    = (const float*)d_in[15];
  const float* asrc3 = (const float*)d_in[16];
  const float* adst3 = (const float*)d_in[17];
  const float* b3    = (const float*)d_in[18];
  const float* g3    = (const float*)d_in[19];
  const float* be3   = (const float*)d_in[20];
  const float* Wp    = (const float*)d_in[21];
  const float* bp    = (const float*)d_in[22];

  const int N = in_sizes[0] / 128;
  const int E = in_sizes[1] / 2;
  const int G = out_size / 128;
  const int EN = E + N;

  char* ws = (char*)d_ws;
  size_t off = 0;
  auto alloc = [&](size_t bytes) -> char* {
    char* p = ws + off;
    off = (off + bytes + 255) & ~(size_t)255;
    return p;
  };
  // region0: x_bf (N*128 bf16) lives here until aggw-L1 overwrites it with h_bf (N*256 bf16)
  ushort*   region0  = (ushort*)alloc((size_t)N * 256 * 2);
  ushort*   x_bf     = region0;
  ushort*   h_bf     = region0;
  ushort*   xbufA    = (ushort*)alloc((size_t)N * 256 * 2);  // xl (bf16)
  float*    xbufB    = (float*)alloc((size_t)N * 128 * 4);   // layer-3 output (f32, for pooling)
  float*    al       = (float*)alloc((size_t)N * 4 * 4);
  float*    ar       = (float*)alloc((size_t)N * 4 * 4);
  int*      deg      = (int*)alloc((size_t)N * 4);
  int*      row_ptr  = (int*)alloc((size_t)(N + 1) * 4);
  int*      cursor   = (int*)alloc((size_t)N * 4);
  int*      csr_src  = (int*)alloc((size_t)EN * 4);
  int*      pos      = (int*)alloc((size_t)(G + 1) * 4);
  float*    pool_sum = (float*)alloc((size_t)G * 128 * 4);
  unsigned* pool_max = (unsigned*)alloc((size_t)G * 128 * 4);
  ushort*   W1t      = (ushort*)alloc((size_t)256 * 128 * 2);  // [N=256][K=128]
  ushort*   W2t      = (ushort*)alloc((size_t)256 * 256 * 2);  // [256][256]
  ushort*   W3t      = (ushort*)alloc((size_t)128 * 256 * 2);  // [128][256]

  hipMemsetAsync(deg, 0, (size_t)N * 4, stream);
  hipMemsetAsync(pool_sum, 0, (size_t)G * 128 * 4, stream);
  hipMemsetAsync(pool_max, 0, (size_t)G * 128 * 4, stream);

  // CSR build + graph bounds + dtype prep
  k_deg<<<(EN + 255) / 256, 256, 0, stream>>>(ei, deg, E, N);
  k_scan<<<1, 1024, 0, stream>>>(deg, row_ptr, cursor, N);
  k_scatter<<<(EN + 255) / 256, 256, 0, stream>>>(ei, cursor, csr_src, E, N);
  k_bounds<<<1, 128, 0, stream>>>(batch, pos, N, G);
  k_cast<<<(N * 128 / 4 + 255) / 256, 256, 0, stream>>>(x, x_bf, N * 128 / 4);
  k_wt<<<(128 * 256 + 255) / 256, 256, 0, stream>>>(W1, W1t, 128, 256);
  k_wt<<<(256 * 256 + 255) / 256, 256, 0, stream>>>(W2, W2t, 256, 256);
  k_wt<<<(256 * 128 + 255) / 256, 256, 0, stream>>>(W3, W3t, 256, 128);

  const int MB = (N + 127) / 128;
  const int NB4 = (N + 3) / 4;

  // Layer 1: 128 -> 256, H=4, C=64
  k_mm<128, 256><<<dim3(MB, 2), 256, 0, stream>>>(x_bf, W1t, xbufA, N);
  k_coef<4, 256><<<NB4, 256, 0, stream>>>(xbufA, asrc1, adst1, al, ar, N);
  k_aggw<4, 256, true><<<NB4, 256, 0, stream>>>(xbufA, al, ar, row_ptr, csr_src, b1, g1, be1, (float*)h_bf, N);

  // Layer 2: 256 -> 256, H=4, C=64
  k_mm<256, 256><<<dim3(MB, 2), 256, 0, stream>>>(h_bf, W2t, xbufA, N);
  k_coef<4, 256><<<NB4, 256, 0, stream>>>(xbufA, asrc2, adst2, al, ar, N);
  k_aggw<4, 256, true><<<NB4, 256, 0, stream>>>(xbufA, al, ar, row_ptr, csr_src, b2, g2, be2, (float*)h_bf, N);

  // Layer 3: 256 -> 128, H=1, C=128
  k_mm<256, 128><<<dim3(MB, 1), 256, 0, stream>>>(h_bf, W3t, xbufA, N);
  k_coef<1, 128><<<NB4, 256, 0, stream>>>(xbufA, asrc3, adst3, al, ar, N);
  k_aggw<1, 128, false><<<NB4, 256, 0, stream>>>(xbufA, al, ar, row_ptr, csr_src, b3, g3, be3, xbufB, N);

  // Pooling + final projection
  k_pool<<<G * 4, 128, 0, stream>>>(xbufB, pos, pool_sum, pool_max);
  k_final<<<G, 128, 0, stream>>>(pool_sum, pool_max, pos, Wp, bp, (float*)d_out);
}

// Round 7
// 482.899 us; speedup vs baseline: 3.4086x; 1.2029x over previous
//
#include <hip/hip_runtime.h>

#define EPS_LN 1e-5f
typedef unsigned int uint;

using bf16x8 = __attribute__((ext_vector_type(8))) short;
using f32x4  = __attribute__((ext_vector_type(4))) float;

__device__ inline float bf2f(ushort h){ return __uint_as_float(((uint)h) << 16); }
__device__ inline ushort f2bf(float f){
  uint u = __float_as_uint(f);
  u += 0x7fffu + ((u >> 16) & 1u);   // round-to-nearest-even
  return (ushort)(u >> 16);
}

// ---------------- CSR build (dst-indexed) ----------------
__global__ void k_deg(const int* __restrict__ ei, int* __restrict__ deg, int E, int N){
  int e = blockIdx.x * 256 + threadIdx.x;
  if (e >= E + N) return;
  int dst = (e < E) ? ei[E + e] : (e - E);   // self loops appended
  atomicAdd(&deg[dst], 1);
}

// ---- parallel scan: block sums -> tiny scan -> per-block rescan ----
__global__ __launch_bounds__(1024) void k_bsum(const int* __restrict__ deg, int* __restrict__ bsum, int n){
  __shared__ int ws[16];
  const int t = (int)threadIdx.x, lane = t & 63, w = t >> 6;
  int i = blockIdx.x * 1024 + t;
  int v = (i < n) ? deg[i] : 0;
  #pragma unroll
  for (int off = 32; off; off >>= 1) v += __shfl_xor(v, off);
  if (lane == 0) ws[w] = v;
  __syncthreads();
  if (t == 0){
    int s = 0;
    #pragma unroll
    for (int k = 0; k < 16; k++) s += ws[k];
    bsum[blockIdx.x] = s;
  }
}

__global__ __launch_bounds__(64) void k_bscan(int* __restrict__ bsum, int nb){
  const int lane = (int)threadIdx.x;
  int carry = 0;
  for (int b0 = 0; b0 < nb; b0 += 64){
    int i = b0 + lane;
    int v = (i < nb) ? bsum[i] : 0;
    int s = v;
    #pragma unroll
    for (int off = 1; off < 64; off <<= 1){ int u = __shfl_up(s, off); if (lane >= off) s += u; }
    if (i < nb) bsum[i] = s - v + carry;   // exclusive
    carry += __shfl(s, 63);
  }
}

__global__ __launch_bounds__(1024) void k_scan2(const int* __restrict__ deg, const int* __restrict__ bpre,
                                                int* __restrict__ row_ptr, int* __restrict__ cursor, int n){
  __shared__ int wsum[16];
  const int t = (int)threadIdx.x, lane = t & 63, w = t >> 6;
  int i = blockIdx.x * 1024 + t;
  int v = (i < n) ? deg[i] : 0;
  int s = v;
  #pragma unroll
  for (int off = 1; off < 64; off <<= 1){ int u = __shfl_up(s, off); if (lane >= off) s += u; }
  if (lane == 63) wsum[w] = s;
  __syncthreads();
  if (w == 0 && lane < 16){
    int sc = wsum[lane];
    #pragma unroll
    for (int off = 1; off < 16; off <<= 1){ int u = __shfl_up(sc, off); if (lane >= off) sc += u; }
    wsum[lane] = sc;
  }
  __syncthreads();
  int prefix = bpre[blockIdx.x] + (w ? wsum[w - 1] : 0) + s;   // inclusive
  if (i < n){ row_ptr[i + 1] = prefix; cursor[i] = prefix - v; }
  if (i == 0) row_ptr[0] = 0;
}

__global__ void k_scatter(const int* __restrict__ ei, int* __restrict__ cursor,
                          int* __restrict__ csr_src, int E, int N){
  int e = blockIdx.x * 256 + threadIdx.x;
  if (e >= E + N) return;
  int src, dst;
  if (e < E){ src = ei[e]; dst = ei[E + e]; } else { src = dst = e - E; }
  int pos = atomicAdd(&cursor[dst], 1);
  csr_src[pos] = src;
}

// ---------------- graph segment bounds via binary search (batch is sorted) ----------------
__global__ void k_bounds(const int* __restrict__ batch, int* __restrict__ pos, int N, int G){
  int g = (int)threadIdx.x;
  if (g > G) return;
  int lo = 0, hi = N;             // first i with batch[i] >= g
  while (lo < hi){
    int mid = (lo + hi) >> 1;
    if (batch[mid] < g) lo = mid + 1; else hi = mid;
  }
  pos[g] = lo;
}

// ---------------- dtype prep ----------------
__global__ void k_cast(const float* __restrict__ in, ushort* __restrict__ out, int n4){
  int i = blockIdx.x * 256 + threadIdx.x;
  if (i >= n4) return;
  float4 v = reinterpret_cast<const float4*>(in)[i];
  ushort4 o;
  o.x = f2bf(v.x); o.y = f2bf(v.y); o.z = f2bf(v.z); o.w = f2bf(v.w);
  reinterpret_cast<ushort4*>(out)[i] = o;
}

// Wt[n][k] (bf16) = W[k][n] (f32)
__global__ void k_wt(const float* __restrict__ W, ushort* __restrict__ Wt, int K, int N){
  int idx = blockIdx.x * 256 + threadIdx.x;
  if (idx >= K * N) return;
  int n = idx / K, k = idx - n * K;
  Wt[idx] = f2bf(W[(size_t)k * N + n]);
}

// ---------------- MFMA GEMM: out[M,N](bf16) = A[M,K](bf16) @ W[K,N], W given as Wt[N,K](bf16) ----
template<int K, int N>
__global__ __launch_bounds__(256, 2) void k_mm(const ushort* __restrict__ A,
                                               const ushort* __restrict__ Wt,
                                               ushort* __restrict__ out, int M)
{
  __shared__ __align__(16) ushort ldsA[128 * 128];
  __shared__ __align__(16) ushort ldsB[128 * 128];

  const int t = (int)threadIdx.x;
  const int lane = t & 63;
  const int w = t >> 6;
  const int wm = w >> 1, wn = w & 1;
  const int row0 = blockIdx.x * 128;
  const int n0 = blockIdx.y * 128;
  const int trow = t >> 4;     // 0..15
  const int tk = t & 15;       // kb8 index

  f32x4 acc[4][4];
  #pragma unroll
  for (int mt = 0; mt < 4; mt++)
    #pragma unroll
    for (int nt = 0; nt < 4; nt++)
      acc[mt][nt] = (f32x4){0.f, 0.f, 0.f, 0.f};

  #pragma unroll
  for (int kt = 0; kt < K / 128; kt++){
    uint4 ra[8], rb[8];
    #pragma unroll
    for (int p = 0; p < 8; p++){
      int arow = p * 16 + trow;
      int grow = row0 + arow; if (grow > M - 1) grow = M - 1;
      ra[p] = *reinterpret_cast<const uint4*>(&A[(size_t)grow * K + kt * 128 + tk * 8]);
      rb[p] = *reinterpret_cast<const uint4*>(&Wt[(size_t)(n0 + arow) * K + kt * 128 + tk * 8]);
    }
    if (kt) __syncthreads();          // previous tile fully consumed
    #pragma unroll
    for (int p = 0; p < 8; p++){
      int arow = p * 16 + trow;
      int sw = (tk ^ (arow & 7)) * 8;
      *reinterpret_cast<uint4*>(&ldsA[arow * 128 + sw]) = ra[p];
      *reinterpret_cast<uint4*>(&ldsB[arow * 128 + sw]) = rb[p];
    }
    __syncthreads();

    #pragma unroll
    for (int ks = 0; ks < 4; ks++){
      bf16x8 af[4], bfr[4];
      const int kb8 = ks * 4 + (lane >> 4);
      #pragma unroll
      for (int mt = 0; mt < 4; mt++){
        int arow = wm * 64 + mt * 16 + (lane & 15);
        af[mt] = *reinterpret_cast<const bf16x8*>(&ldsA[arow * 128 + ((kb8 ^ (arow & 7)) * 8)]);
        int brow = wn * 64 + mt * 16 + (lane & 15);
        bfr[mt] = *reinterpret_cast<const bf16x8*>(&ldsB[brow * 128 + ((kb8 ^ (brow & 7)) * 8)]);
      }
      #pragma unroll
      for (int mt = 0; mt < 4; mt++)
        #pragma unroll
        for (int nt = 0; nt < 4; nt++)
          acc[mt][nt] = __builtin_amdgcn_mfma_f32_16x16x32_bf16(af[mt], bfr[nt], acc[mt][nt], 0, 0, 0);
    }
  }

  // epilogue: C/D map col=lane&15, row=(lane>>4)*4+r  (m89-verified)
  #pragma unroll
  for (int mt = 0; mt < 4; mt++){
    const int grow_b = row0 + wm * 64 + mt * 16 + (lane >> 4) * 4;
    #pragma unroll
    for (int nt = 0; nt < 4; nt++){
      const int gcol = n0 + wn * 64 + nt * 16 + (lane & 15);
      #pragma unroll
      for (int r = 0; r < 4; r++){
        int grow = grow_b + r;
        if (grow < M) out[(size_t)grow * N + gcol] = f2bf(acc[mt][nt][r]);
      }
    }
  }
}

// ---------------- attention coefficients from bf16 xl ----------------
template<int H, int DIM>
__global__ __launch_bounds__(256) void k_coef(const ushort* __restrict__ xl,
    const float* __restrict__ asrc, const float* __restrict__ adst,
    float* __restrict__ al, float* __restrict__ ar, int N)
{
  constexpr int EPL = DIM / 64;       // elems per lane (4 or 2)
  constexpr int C = DIM / H;
  constexpr int LG = C / EPL;         // lanes per head group
  const int lane = (int)threadIdx.x & 63;
  const int n = blockIdx.x * 4 + ((int)threadIdx.x >> 6);
  if (n >= N) return;
  const size_t base = (size_t)n * DIM + lane * EPL;
  ushort xv[EPL];
  if constexpr (EPL == 4){ *reinterpret_cast<uint2*>(xv) = *reinterpret_cast<const uint2*>(&xl[base]); }
  else                   { *reinterpret_cast<uint*>(xv)  = *reinterpret_cast<const uint*>(&xl[base]); }
  float pa = 0.f, pb = 0.f;
  #pragma unroll
  for (int j = 0; j < EPL; j++){
    float x = bf2f(xv[j]);
    pa = fmaf(x, asrc[lane * EPL + j], pa);
    pb = fmaf(x, adst[lane * EPL + j], pb);
  }
  #pragma unroll
  for (int off = 1; off < LG; off <<= 1){ pa += __shfl_xor(pa, off); pb += __shfl_xor(pb, off); }
  if ((lane & (LG - 1)) == 0){
    int h = lane / LG;
    al[(size_t)n * H + h] = pa;
    ar[(size_t)n * H + h] = pb;
  }
}

// ---- gather helpers: one edge row contribution ----
template<int DIM>
__device__ inline void gstep4(const char* __restrict__ xlb, int laneB, int s, float p, float* acc){
  uint2 v = *reinterpret_cast<const uint2*>(xlb + (size_t)((uint)s * (uint)(DIM * 2)) + laneB);
  acc[0] = fmaf(p, __uint_as_float(v.x << 16), acc[0]);
  acc[1] = fmaf(p, __uint_as_float(v.x & 0xffff0000u), acc[1]);
  acc[2] = fmaf(p, __uint_as_float(v.y << 16), acc[2]);
  acc[3] = fmaf(p, __uint_as_float(v.y & 0xffff0000u), acc[3]);
}
template<int DIM>
__device__ inline void gstep2(const char* __restrict__ xlb, int laneB, int s, float p, float* acc){
  uint v = *reinterpret_cast<const uint*>(xlb + (size_t)((uint)s * (uint)(DIM * 2)) + laneB);
  acc[0] = fmaf(p, __uint_as_float(v << 16), acc[0]);
  acc[1] = fmaf(p, __uint_as_float(v & 0xffff0000u), acc[1]);
}

// ---------------- per-node wave gather: softmax + aggregate + bias + LN + ReLU ----------------
// One WAVE per node (4 waves/block, independent). No block barriers.
template<int H, int DIM, bool BF16_OUT>
__global__ __launch_bounds__(256) void k_aggw(
    const ushort* __restrict__ xl,
    const float* __restrict__ al, const float* __restrict__ ar,
    const int* __restrict__ row_ptr, const int* __restrict__ csr_src,
    const float* __restrict__ bias, const float* __restrict__ gamma, const float* __restrict__ beta,
    float* __restrict__ out, int N)
{
  constexpr int EPL = DIM / 64;        // cols per lane: 4 (DIM=256) or 2 (DIM=128)
  const int tid = (int)threadIdx.x;
  const int wid = tid >> 6, lane = tid & 63;
  __shared__ float plds_all[4][H * 64];
  float* plds = plds_all[wid];
  const int n = blockIdx.x * 4 + wid;
  if (n >= N) return;
  const int start = __builtin_amdgcn_readfirstlane(row_ptr[n]);
  const int end   = __builtin_amdgcn_readfirstlane(row_ptr[n + 1]);
  const int deg   = end - start;
  const int hm    = (H == 4) ? (lane >> 4) : 0;
  const int laneB = lane * (EPL * 2);

  float arv[H];
  #pragma unroll
  for (int h = 0; h < H; h++) arv[h] = ar[(size_t)n * H + h];

  float acc[EPL];
  #pragma unroll
  for (int e = 0; e < EPL; e++) acc[e] = 0.f;
  float psum[H];
  const char* xlb = (const char*)xl;

  auto gather = [&](int base, int cnt){
    int j = 0;
    for (; j + 4 <= cnt; j += 4){
      int s0 = csr_src[base + j + 0], s1 = csr_src[base + j + 1];
      int s2 = csr_src[base + j + 2], s3 = csr_src[base + j + 3];
      float q0 = plds[hm * 64 + j + 0], q1 = plds[hm * 64 + j + 1];
      float q2 = plds[hm * 64 + j + 2], q3 = plds[hm * 64 + j + 3];
      if constexpr (EPL == 4){
        gstep4<DIM>(xlb, laneB, s0, q0, acc); gstep4<DIM>(xlb, laneB, s1, q1, acc);
        gstep4<DIM>(xlb, laneB, s2, q2, acc); gstep4<DIM>(xlb, laneB, s3, q3, acc);
      } else {
        gstep2<DIM>(xlb, laneB, s0, q0, acc); gstep2<DIM>(xlb, laneB, s1, q1, acc);
        gstep2<DIM>(xlb, laneB, s2, q2, acc); gstep2<DIM>(xlb, laneB, s3, q3, acc);
      }
    }
    for (; j < cnt; j++){
      int s0 = csr_src[base + j];
      float q0 = plds[hm * 64 + j];
      if constexpr (EPL == 4) gstep4<DIM>(xlb, laneB, s0, q0, acc);
      else                    gstep2<DIM>(xlb, laneB, s0, q0, acc);
    }
  };

  if (deg <= 64){
    // ---- fast path: one al gather; e/p in registers ----
    int ii = start + (lane < deg ? lane : deg - 1);
    int src = csr_src[ii];
    float e[H];
    if constexpr (H == 4){
      float4 a4 = *reinterpret_cast<const float4*>(&al[(size_t)src * 4]);
      e[0] = a4.x + arv[0]; e[1] = a4.y + arv[1]; e[2] = a4.z + arv[2]; e[3] = a4.w + arv[3];
    } else {
      e[0] = al[src] + arv[0];
    }
    #pragma unroll
    for (int h = 0; h < H; h++){
      e[h] = e[h] > 0.f ? e[h] : 0.2f * e[h];
      if (lane >= deg) e[h] = -1e30f;
    }
    float mx[H];
    #pragma unroll
    for (int h = 0; h < H; h++){
      mx[h] = e[h];
      #pragma unroll
      for (int off = 32; off; off >>= 1) mx[h] = fmaxf(mx[h], __shfl_xor(mx[h], off));
    }
    #pragma unroll
    for (int h = 0; h < H; h++){
      float p = (lane < deg) ? __expf(e[h] - mx[h]) : 0.f;
      plds[h * 64 + lane] = p;
      psum[h] = p;
      #pragma unroll
      for (int off = 32; off; off >>= 1) psum[h] += __shfl_xor(psum[h], off);
    }
    __asm__ volatile("s_waitcnt lgkmcnt(0)" ::: "memory");
    __builtin_amdgcn_wave_barrier();
    gather(start, deg);
  } else {
    // ---- slow path (deg > 64, rare): global max pass then chunked ----
    float mx[H];
    #pragma unroll
    for (int h = 0; h < H; h++) mx[h] = -1e30f;
    for (int i = start + lane; i < end; i += 64){
      int src = csr_src[i];
      if constexpr (H == 4){
        float4 a4 = *reinterpret_cast<const float4*>(&al[(size_t)src * 4]);
        float e0 = a4.x + arv[0]; e0 = e0 > 0.f ? e0 : 0.2f * e0; mx[0] = fmaxf(mx[0], e0);
        float e1 = a4.y + arv[1]; e1 = e1 > 0.f ? e1 : 0.2f * e1; mx[1] = fmaxf(mx[1], e1);
        float e2 = a4.z + arv[2]; e2 = e2 > 0.f ? e2 : 0.2f * e2; mx[2] = fmaxf(mx[2], e2);
        float e3 = a4.w + arv[3]; e3 = e3 > 0.f ? e3 : 0.2f * e3; mx[3] = fmaxf(mx[3], e3);
      } else {
        float e = al[src] + arv[0]; e = e > 0.f ? e : 0.2f * e; mx[0] = fmaxf(mx[0], e);
      }
    }
    #pragma unroll
    for (int h = 0; h < H; h++){
      #pragma unroll
      for (int off = 32; off; off >>= 1) mx[h] = fmaxf(mx[h], __shfl_xor(mx[h], off));
    }
    #pragma unroll
    for (int h = 0; h < H; h++) psum[h] = 0.f;
    for (int c0 = start; c0 < end; c0 += 64){
      const int cnt = min(64, end - c0);
      __asm__ volatile("s_waitcnt lgkmcnt(0)" ::: "memory");   // prev chunk consumed
      __builtin_amdgcn_wave_barrier();
      if (lane < cnt){
        int src = csr_src[c0 + lane];
        if constexpr (H == 4){
          float4 a4 = *reinterpret_cast<const float4*>(&al[(size_t)src * 4]);
          float e0 = a4.x + arv[0]; e0 = e0 > 0.f ? e0 : 0.2f * e0; float p0 = __expf(e0 - mx[0]);
          float e1 = a4.y + arv[1]; e1 = e1 > 0.f ? e1 : 0.2f * e1; float p1 = __expf(e1 - mx[1]);
          float e2 = a4.z + arv[2]; e2 = e2 > 0.f ? e2 : 0.2f * e2; float p2 = __expf(e2 - mx[2]);
          float e3 = a4.w + arv[3]; e3 = e3 > 0.f ? e3 : 0.2f * e3; float p3 = __expf(e3 - mx[3]);
          plds[0 * 64 + lane] = p0; plds[1 * 64 + lane] = p1;
          plds[2 * 64 + lane] = p2; plds[3 * 64 + lane] = p3;
          psum[0] += p0; psum[1] += p1; psum[2] += p2; psum[3] += p3;
        } else {
          float e = al[src] + arv[0]; e = e > 0.f ? e : 0.2f * e; float p = __expf(e - mx[0]);
          plds[lane] = p; psum[0] += p;
        }
      }
      __asm__ volatile("s_waitcnt lgkmcnt(0)" ::: "memory");
      __builtin_amdgcn_wave_barrier();
      gather(c0, cnt);
    }
    #pragma unroll
    for (int h = 0; h < H; h++){
      #pragma unroll
      for (int off = 32; off; off >>= 1) psum[h] += __shfl_xor(psum[h], off);
    }
  }

  // ---- normalize ----
  float ssel;
  if constexpr (H == 4){
    ssel = (hm == 0) ? psum[0] : (hm == 1) ? psum[1] : (hm == 2) ? psum[2] : psum[3];
  } else {
    ssel = psum[0];
  }
  const float inv = 1.f / (ssel + 1e-16f);

  // ---- bias + LayerNorm + ReLU (all-shuffle, no LDS) ----
  float v[EPL];
  if constexpr (EPL == 4){
    float4 bb = *reinterpret_cast<const float4*>(&bias[lane * 4]);
    v[0] = fmaf(acc[0], inv, bb.x); v[1] = fmaf(acc[1], inv, bb.y);
    v[2] = fmaf(acc[2], inv, bb.z); v[3] = fmaf(acc[3], inv, bb.w);
  } else {
    float2 bb = *reinterpret_cast<const float2*>(&bias[lane * 2]);
    v[0] = fmaf(acc[0], inv, bb.x); v[1] = fmaf(acc[1], inv, bb.y);
  }
  float s1 = 0.f, s2 = 0.f;
  #pragma unroll
  for (int e = 0; e < EPL; e++){ s1 += v[e]; s2 += v[e] * v[e]; }
  #pragma unroll
  for (int off = 32; off; off >>= 1){ s1 += __shfl_xor(s1, off); s2 += __shfl_xor(s2, off); }
  const float mu = s1 / DIM;
  const float rstd = rsqrtf(s2 / DIM - mu * mu + EPS_LN);

  if constexpr (EPL == 4){
    float4 gg = *reinterpret_cast<const float4*>(&gamma[lane * 4]);
    float4 be = *reinterpret_cast<const float4*>(&beta[lane * 4]);
    float o0 = fmaxf((v[0] - mu) * rstd * gg.x + be.x, 0.f);
    float o1 = fmaxf((v[1] - mu) * rstd * gg.y + be.y, 0.f);
    float o2 = fmaxf((v[2] - mu) * rstd * gg.z + be.z, 0.f);
    float o3 = fmaxf((v[3] - mu) * rstd * gg.w + be.w, 0.f);
    if constexpr (BF16_OUT){
      uint2 pk;
      pk.x = (uint)f2bf(o0) | ((uint)f2bf(o1) << 16);
      pk.y = (uint)f2bf(o2) | ((uint)f2bf(o3) << 16);
      *reinterpret_cast<uint2*>(&reinterpret_cast<ushort*>(out)[(size_t)n * DIM + lane * 4]) = pk;
    } else {
      *reinterpret_cast<float4*>(&out[(size_t)n * DIM + lane * 4]) = make_float4(o0, o1, o2, o3);
    }
  } else {
    float2 gg = *reinterpret_cast<const float2*>(&gamma[lane * 2]);
    float2 be = *reinterpret_cast<const float2*>(&beta[lane * 2]);
    float o0 = fmaxf((v[0] - mu) * rstd * gg.x + be.x, 0.f);
    float o1 = fmaxf((v[1] - mu) * rstd * gg.y + be.y, 0.f);
    if constexpr (BF16_OUT){
      uint pk = (uint)f2bf(o0) | ((uint)f2bf(o1) << 16);
      reinterpret_cast<uint*>(out)[(size_t)n * (DIM / 2) + lane] = pk;
    } else {
      *reinterpret_cast<float2*>(&out[(size_t)n * DIM + lane * 2]) = make_float2(o0, o1);
    }
  }
}

// ---------------- pooling over pos ranges ----------------
__global__ __launch_bounds__(128) void k_pool(const float* __restrict__ h, const int* __restrict__ pos,
    float* __restrict__ pool_sum, unsigned* __restrict__ pool_max){
  const int c = (int)threadIdx.x;           // channel 0..127
  const int g = blockIdx.x >> 2;            // graph
  const int q = blockIdx.x & 3;             // quarter
  const int s = pos[g], e = pos[g + 1];
  const int len = e - s;
  if (len <= 0) return;
  const int chunk = (len + 3) >> 2;
  const int n0 = s + q * chunk;
  const int n1 = min(n0 + chunk, e);
  if (n0 >= n1) return;
  float sum = 0.f, mx = 0.f;                // post-ReLU values >= 0
  for (int n = n0; n < n1; n++){
    float v = h[(size_t)n * 128 + c];
    sum += v; mx = fmaxf(mx, v);
  }
  atomicAdd(&pool_sum[g * 128 + c], sum);
  atomicMax(&pool_max[g * 128 + c], __float_as_uint(mx));
}

__global__ __launch_bounds__(128) void k_final(const float* __restrict__ pool_sum,
    const unsigned* __restrict__ pool_max, const int* __restrict__ pos,
    const float* __restrict__ Wp, const float* __restrict__ bp, float* __restrict__ out){
  const int g = blockIdx.x;
  const int j = (int)threadIdx.x;
  float inv = 1.f / fmaxf((float)(pos[g + 1] - pos[g]), 1.f);
  float acc = bp[j];
  #pragma unroll 4
  for (int k = 0; k < 128; k++)
    acc = fmaf(pool_sum[g * 128 + k] * inv, Wp[k * 128 + j], acc);
  #pragma unroll 4
  for (int k = 0; k < 128; k++)
    acc = fmaf(__uint_as_float(pool_max[g * 128 + k]), Wp[(128 + k) * 128 + j], acc);
  out[g * 128 + j] = acc;
}

// ---------------- launch ----------------
extern "C" void kernel_launch(void* const* d_in, const int* in_sizes, int n_in,
                              void* d_out, int out_size, void* d_ws, size_t ws_size,
                              hipStream_t stream){
  const float* x     = (const float*)d_in[0];
  const int*   ei    = (const int*)d_in[1];
  const int*   batch = (const int*)d_in[2];
  const float* W1    = (const float*)d_in[3];
  const float* asrc1 = (const float*)d_in[4];
  const float* adst1 = (const float*)d_in[5];
  const float* b1    = (const float*)d_in[6];
  const float* g1    = (const float*)d_in[7];
  const float* be1   = (const float*)d_in[8];
  const float* W2    = (const float*)d_in[9];
  const float* asrc2 = (const float*)d_in[10];
  const float* adst2 = (const float*)d_in[11];
  const float* b2    = (const float*)d_in[12];
  const float* g2    = (const float*)d_in[13];
  const float* be2   = (const float*)d_in[14];
  const float* W3    = (const float*)d_in[15];
  const float* asrc3 = (const float*)d_in[16];
  const float* adst3 = (const float*)d_in[17];
  const float* b3    = (const float*)d_in[18];
  const float* g3    = (const float*)d_in[19];
  const float* be3   = (const float*)d_in[20];
  const float* Wp    = (const float*)d_in[21];
  const float* bp    = (const float*)d_in[22];

  const int N = in_sizes[0] / 128;
  const int E = in_sizes[1] / 2;
  const int G = out_size / 128;
  const int EN = E + N;

  char* ws = (char*)d_ws;
  size_t off = 0;
  auto alloc = [&](size_t bytes) -> char* {
    char* p = ws + off;
    off = (off + bytes + 255) & ~(size_t)255;
    return p;
  };
  // region0: x_bf (N*128 bf16) lives here until aggw-L1 overwrites it with h_bf (N*256 bf16)
  ushort*   region0  = (ushort*)alloc((size_t)N * 256 * 2);
  ushort*   x_bf     = region0;
  ushort*   h_bf     = region0;
  ushort*   xbufA    = (ushort*)alloc((size_t)N * 256 * 2);  // xl (bf16)
  float*    xbufB    = (float*)alloc((size_t)N * 128 * 4);   // layer-3 output (f32, for pooling)
  float*    al       = (float*)alloc((size_t)N * 4 * 4);
  float*    ar       = (float*)alloc((size_t)N * 4 * 4);
  int*      deg      = (int*)alloc((size_t)N * 4);
  int*      row_ptr  = (int*)alloc((size_t)(N + 1) * 4);
  int*      cursor   = (int*)alloc((size_t)N * 4);
  int*      csr_src  = (int*)alloc((size_t)EN * 4);
  int*      pos      = (int*)alloc((size_t)(G + 1) * 4);
  float*    pool_sum = (float*)alloc((size_t)G * 128 * 4);
  unsigned* pool_max = (unsigned*)alloc((size_t)G * 128 * 4);
  ushort*   W1t      = (ushort*)alloc((size_t)256 * 128 * 2);  // [N=256][K=128]
  ushort*   W2t      = (ushort*)alloc((size_t)256 * 256 * 2);  // [256][256]
  ushort*   W3t      = (ushort*)alloc((size_t)128 * 256 * 2);  // [128][256]
  const int NB = (N + 1023) / 1024;
  int*      bsum     = (int*)alloc((size_t)NB * 4);

  hipMemsetAsync(deg, 0, (size_t)N * 4, stream);
  hipMemsetAsync(pool_sum, 0, (size_t)G * 128 * 4, stream);
  hipMemsetAsync(pool_max, 0, (size_t)G * 128 * 4, stream);

  // CSR build + graph bounds + dtype prep
  k_deg<<<(EN + 255) / 256, 256, 0, stream>>>(ei, deg, E, N);
  k_bsum<<<NB, 1024, 0, stream>>>(deg, bsum, N);
  k_bscan<<<1, 64, 0, stream>>>(bsum, NB);
  k_scan2<<<NB, 1024, 0, stream>>>(deg, bsum, row_ptr, cursor, N);
  k_scatter<<<(EN + 255) / 256, 256, 0, stream>>>(ei, cursor, csr_src, E, N);
  k_bounds<<<1, 128, 0, stream>>>(batch, pos, N, G);
  k_cast<<<(N * 128 / 4 + 255) / 256, 256, 0, stream>>>(x, x_bf, N * 128 / 4);
  k_wt<<<(128 * 256 + 255) / 256, 256, 0, stream>>>(W1, W1t, 128, 256);
  k_wt<<<(256 * 256 + 255) / 256, 256, 0, stream>>>(W2, W2t, 256, 256);
  k_wt<<<(256 * 128 + 255) / 256, 256, 0, stream>>>(W3, W3t, 256, 128);

  const int MB = (N + 127) / 128;
  const int NB4 = (N + 3) / 4;

  // Layer 1: 128 -> 256, H=4, C=64
  k_mm<128, 256><<<dim3(MB, 2), 256, 0, stream>>>(x_bf, W1t, xbufA, N);
  k_coef<4, 256><<<NB4, 256, 0, stream>>>(xbufA, asrc1, adst1, al, ar, N);
  k_aggw<4, 256, true><<<NB4, 256, 0, stream>>>(xbufA, al, ar, row_ptr, csr_src, b1, g1, be1, (float*)h_bf, N);

  // Layer 2: 256 -> 256, H=4, C=64
  k_mm<256, 256><<<dim3(MB, 2), 256, 0, stream>>>(h_bf, W2t, xbufA, N);
  k_coef<4, 256><<<NB4, 256, 0, stream>>>(xbufA, asrc2, adst2, al, ar, N);
  k_aggw<4, 256, true><<<NB4, 256, 0, stream>>>(xbufA, al, ar, row_ptr, csr_src, b2, g2, be2, (float*)h_bf, N);

  // Layer 3: 256 -> 128, H=1, C=128
  k_mm<256, 128><<<dim3(MB, 1), 256, 0, stream>>>(h_bf, W3t, xbufA, N);
  k_coef<1, 128><<<NB4, 256, 0, stream>>>(xbufA, asrc3, adst3, al, ar, N);
  k_aggw<1, 128, false><<<NB4, 256, 0, stream>>>(xbufA, al, ar, row_ptr, csr_src, b3, g3, be3, xbufB, N);

  // Pooling + final projection
  k_pool<<<G * 4, 128, 0, stream>>>(xbufB, pos, pool_sum, pool_max);
  k_final<<<G, 128, 0, stream>>>(pool_sum, pool_max, pos, Wp, bp, (float*)d_out);
}

// Round 8
// 462.528 us; speedup vs baseline: 3.5587x; 1.0440x over previous
//
#include <hip/hip_runtime.h>

#define EPS_LN 1e-5f
typedef unsigned int uint;

using bf16x8 = __attribute__((ext_vector_type(8))) short;
using f32x4  = __attribute__((ext_vector_type(4))) float;

__device__ inline float bf2f(ushort h){ return __uint_as_float(((uint)h) << 16); }
__device__ inline ushort f2bf(float f){
  uint u = __float_as_uint(f);
  u += 0x7fffu + ((u >> 16) & 1u);   // round-to-nearest-even
  return (ushort)(u >> 16);
}

// ---------------- CSR build (dst-indexed) ----------------
__global__ void k_deg(const int* __restrict__ ei, int* __restrict__ deg, int E, int N){
  int e = blockIdx.x * 256 + threadIdx.x;
  if (e >= E + N) return;
  int dst = (e < E) ? ei[E + e] : (e - E);   // self loops appended
  atomicAdd(&deg[dst], 1);
}

__global__ __launch_bounds__(1024) void k_bsum(const int* __restrict__ deg, int* __restrict__ bsum, int n){
  __shared__ int ws[16];
  const int t = (int)threadIdx.x, lane = t & 63, w = t >> 6;
  int i = blockIdx.x * 1024 + t;
  int v = (i < n) ? deg[i] : 0;
  #pragma unroll
  for (int off = 32; off; off >>= 1) v += __shfl_xor(v, off);
  if (lane == 0) ws[w] = v;
  __syncthreads();
  if (t == 0){
    int s = 0;
    #pragma unroll
    for (int k = 0; k < 16; k++) s += ws[k];
    bsum[blockIdx.x] = s;
  }
}

// block 0: exclusive scan of block sums; block 1: graph bounds binary search
__global__ __launch_bounds__(256) void k_misc(int* __restrict__ bsum, int nb,
                                              const int* __restrict__ batch, int* __restrict__ pos,
                                              int N, int G){
  const int t = (int)threadIdx.x;
  if (blockIdx.x == 0){
    if (t >= 64) return;
    const int lane = t;
    int carry = 0;
    for (int b0 = 0; b0 < nb; b0 += 64){
      int i = b0 + lane;
      int v = (i < nb) ? bsum[i] : 0;
      int s = v;
      #pragma unroll
      for (int off = 1; off < 64; off <<= 1){ int u = __shfl_up(s, off); if (lane >= off) s += u; }
      if (i < nb) bsum[i] = s - v + carry;   // exclusive
      carry += __shfl(s, 63);
    }
  } else {
    int g = t;
    if (g > G) return;
    int lo = 0, hi = N;
    while (lo < hi){
      int mid = (lo + hi) >> 1;
      if (batch[mid] < g) lo = mid + 1; else hi = mid;
    }
    pos[g] = lo;
  }
}

__global__ __launch_bounds__(1024) void k_scan2(const int* __restrict__ deg, const int* __restrict__ bpre,
                                                int* __restrict__ row_ptr, int* __restrict__ cursor, int n){
  __shared__ int wsum[16];
  const int t = (int)threadIdx.x, lane = t & 63, w = t >> 6;
  int i = blockIdx.x * 1024 + t;
  int v = (i < n) ? deg[i] : 0;
  int s = v;
  #pragma unroll
  for (int off = 1; off < 64; off <<= 1){ int u = __shfl_up(s, off); if (lane >= off) s += u; }
  if (lane == 63) wsum[w] = s;
  __syncthreads();
  if (w == 0 && lane < 16){
    int sc = wsum[lane];
    #pragma unroll
    for (int off = 1; off < 16; off <<= 1){ int u = __shfl_up(sc, off); if (lane >= off) sc += u; }
    wsum[lane] = sc;
  }
  __syncthreads();
  int prefix = bpre[blockIdx.x] + (w ? wsum[w - 1] : 0) + s;   // inclusive
  if (i < n){ row_ptr[i + 1] = prefix; cursor[i] = prefix - v; }
  if (i == 0) row_ptr[0] = 0;
}

__global__ void k_scatter(const int* __restrict__ ei, int* __restrict__ cursor,
                          int* __restrict__ csr_src, int E, int N){
  int e = blockIdx.x * 256 + threadIdx.x;
  if (e >= E + N) return;
  int src, dst;
  if (e < E){ src = ei[e]; dst = ei[E + e]; } else { src = dst = e - E; }
  int pos = atomicAdd(&cursor[dst], 1);
  csr_src[pos] = src;
}

// ---------------- combined dtype prep: cast x + transpose/cast 3 weights ----------------
__global__ void k_prep(const float* __restrict__ x, ushort* __restrict__ x_bf,
                       const float* __restrict__ W1, ushort* __restrict__ W1t,
                       const float* __restrict__ W2, ushort* __restrict__ W2t,
                       const float* __restrict__ W3, ushort* __restrict__ W3t, int N){
  int i = blockIdx.x * 256 + threadIdx.x;
  const int c0 = N * 32;                    // float4 quads of x
  if (i < c0){
    float4 v = reinterpret_cast<const float4*>(x)[i];
    ushort4 o; o.x = f2bf(v.x); o.y = f2bf(v.y); o.z = f2bf(v.z); o.w = f2bf(v.w);
    reinterpret_cast<ushort4*>(x_bf)[i] = o;
    return;
  }
  i -= c0;
  if (i < 256 * 128){                       // W1t[n*128+k] = W1[k*256+n]
    int n = i >> 7, k = i & 127;
    W1t[i] = f2bf(W1[(size_t)k * 256 + n]);
    return;
  }
  i -= 256 * 128;
  if (i < 256 * 256){                       // W2t[n*256+k] = W2[k*256+n]
    int n = i >> 8, k = i & 255;
    W2t[i] = f2bf(W2[(size_t)k * 256 + n]);
    return;
  }
  i -= 256 * 256;
  if (i < 128 * 256){                       // W3t[n*256+k] = W3[k*128+n]
    int n = i >> 8, k = i & 255;
    W3t[i] = f2bf(W3[(size_t)k * 128 + n]);
  }
}

// ---------------- MFMA GEMM + fused attention-coef epilogue ----------------
// out[M,N](bf16) = A[M,K](bf16) @ Wt[N,K](bf16)^T ; al/ar[row,h] = sum_c acc[row,c]*asrc/adst[c]
template<int K, int N, int H>
__global__ __launch_bounds__(256, 2) void k_mm(const ushort* __restrict__ A,
                                               const ushort* __restrict__ Wt,
                                               ushort* __restrict__ out,
                                               const float* __restrict__ asrc,
                                               const float* __restrict__ adst,
                                               float* __restrict__ al, float* __restrict__ ar,
                                               int M)
{
  constexpr int BANDS = (N / H) / 64;   // 64-col bands per head: 1 (H=4,N=256) or 2 (H=1,N=128)
  __shared__ __align__(16) ushort ldsA[128 * 128];
  __shared__ __align__(16) ushort ldsB[128 * 128];

  const int t = (int)threadIdx.x;
  const int lane = t & 63;
  const int w = t >> 6;
  const int wm = w >> 1, wn = w & 1;
  const int row0 = blockIdx.x * 128;
  const int n0 = blockIdx.y * 128;
  const int trow = t >> 4;     // 0..15
  const int tk = t & 15;       // kb8 index

  f32x4 acc[4][4];
  #pragma unroll
  for (int mt = 0; mt < 4; mt++)
    #pragma unroll
    for (int nt = 0; nt < 4; nt++)
      acc[mt][nt] = (f32x4){0.f, 0.f, 0.f, 0.f};

  #pragma unroll
  for (int kt = 0; kt < K / 128; kt++){
    uint4 ra[8], rb[8];
    #pragma unroll
    for (int p = 0; p < 8; p++){
      int arow = p * 16 + trow;
      int grow = row0 + arow; if (grow > M - 1) grow = M - 1;
      ra[p] = *reinterpret_cast<const uint4*>(&A[(size_t)grow * K + kt * 128 + tk * 8]);
      rb[p] = *reinterpret_cast<const uint4*>(&Wt[(size_t)(n0 + arow) * K + kt * 128 + tk * 8]);
    }
    if (kt) __syncthreads();          // previous tile fully consumed
    #pragma unroll
    for (int p = 0; p < 8; p++){
      int arow = p * 16 + trow;
      int sw = (tk ^ (arow & 7)) * 8;
      *reinterpret_cast<uint4*>(&ldsA[arow * 128 + sw]) = ra[p];
      *reinterpret_cast<uint4*>(&ldsB[arow * 128 + sw]) = rb[p];
    }
    __syncthreads();

    #pragma unroll
    for (int ks = 0; ks < 4; ks++){
      bf16x8 af[4], bfr[4];
      const int kb8 = ks * 4 + (lane >> 4);
      #pragma unroll
      for (int mt = 0; mt < 4; mt++){
        int arow = wm * 64 + mt * 16 + (lane & 15);
        af[mt] = *reinterpret_cast<const bf16x8*>(&ldsA[arow * 128 + ((kb8 ^ (arow & 7)) * 8)]);
        int brow = wn * 64 + mt * 16 + (lane & 15);
        bfr[mt] = *reinterpret_cast<const bf16x8*>(&ldsB[brow * 128 + ((kb8 ^ (brow & 7)) * 8)]);
      }
      #pragma unroll
      for (int mt = 0; mt < 4; mt++)
        #pragma unroll
        for (int nt = 0; nt < 4; nt++)
          acc[mt][nt] = __builtin_amdgcn_mfma_f32_16x16x32_bf16(af[mt], bfr[nt], acc[mt][nt], 0, 0, 0);
    }
  }

  // ---- epilogue 1: C store (C/D map col=lane&15, row=(lane>>4)*4+r, m89-verified) ----
  #pragma unroll
  for (int mt = 0; mt < 4; mt++){
    const int grow_b = row0 + wm * 64 + mt * 16 + (lane >> 4) * 4;
    #pragma unroll
    for (int nt = 0; nt < 4; nt++){
      const int gcol = n0 + wn * 64 + nt * 16 + (lane & 15);
      #pragma unroll
      for (int r = 0; r < 4; r++){
        int grow = grow_b + r;
        if (grow < M) out[(size_t)grow * N + gcol] = f2bf(acc[mt][nt][r]);
      }
    }
  }

  // ---- epilogue 2: fused attention coefficients from f32 accumulators ----
  float av[4], bv[4];
  #pragma unroll
  for (int nt = 0; nt < 4; nt++){
    int col = n0 + wn * 64 + nt * 16 + (lane & 15);
    av[nt] = asrc[col]; bv[nt] = adst[col];
  }
  float paA[4][4], pbA[4][4];     // [mt][r], reduced over the 64-col band
  #pragma unroll
  for (int mt = 0; mt < 4; mt++){
    #pragma unroll
    for (int r = 0; r < 4; r++){
      float pa = acc[mt][0][r] * av[0] + acc[mt][1][r] * av[1]
               + acc[mt][2][r] * av[2] + acc[mt][3][r] * av[3];
      float pb = acc[mt][0][r] * bv[0] + acc[mt][1][r] * bv[1]
               + acc[mt][2][r] * bv[2] + acc[mt][3][r] * bv[3];
      #pragma unroll
      for (int off = 1; off < 16; off <<= 1){ pa += __shfl_xor(pa, off); pb += __shfl_xor(pb, off); }
      paA[mt][r] = pa; pbA[mt][r] = pb;
    }
  }
  if constexpr (BANDS == 1){
    // each (row, head) produced by exactly one wave: plain store
    const int h = (n0 + wn * 64) / (N / H);
    if ((lane & 15) == 0){
      #pragma unroll
      for (int mt = 0; mt < 4; mt++){
        #pragma unroll
        for (int r = 0; r < 4; r++){
          int row = row0 + wm * 64 + mt * 16 + (lane >> 4) * 4 + r;
          if (row < M){
            al[(size_t)row * H + h] = paA[mt][r];
            ar[(size_t)row * H + h] = pbA[mt][r];
          }
        }
      }
    }
  } else {
    // H=1: two column bands (wn=0,1) sum into the same head; combine via LDS
    __syncthreads();                          // ldsA free for reuse
    float* fl = reinterpret_cast<float*>(ldsA);   // 256 floats
    if (wn == 0 && (lane & 15) == 0){
      #pragma unroll
      for (int mt = 0; mt < 4; mt++){
        #pragma unroll
        for (int r = 0; r < 4; r++){
          int rl = wm * 64 + mt * 16 + (lane >> 4) * 4 + r;
          fl[rl] = paA[mt][r]; fl[128 + rl] = pbA[mt][r];
        }
      }
    }
    __syncthreads();
    if (wn == 1 && (lane & 15) == 0){
      #pragma unroll
      for (int mt = 0; mt < 4; mt++){
        #pragma unroll
        for (int r = 0; r < 4; r++){
          int rl = wm * 64 + mt * 16 + (lane >> 4) * 4 + r;
          int row = row0 + rl;
          if (row < M){
            al[row] = fl[rl] + paA[mt][r];
            ar[row] = fl[128 + rl] + pbA[mt][r];
          }
        }
      }
    }
  }
}

// ---- gather helpers: one edge row contribution ----
template<int DIM>
__device__ inline void gstep4(const char* __restrict__ xlb, int laneB, int s, float p, float* acc){
  uint2 v = *reinterpret_cast<const uint2*>(xlb + (size_t)((uint)s * (uint)(DIM * 2)) + laneB);
  acc[0] = fmaf(p, __uint_as_float(v.x << 16), acc[0]);
  acc[1] = fmaf(p, __uint_as_float(v.x & 0xffff0000u), acc[1]);
  acc[2] = fmaf(p, __uint_as_float(v.y << 16), acc[2]);
  acc[3] = fmaf(p, __uint_as_float(v.y & 0xffff0000u), acc[3]);
}
template<int DIM>
__device__ inline void gstep2(const char* __restrict__ xlb, int laneB, int s, float p, float* acc){
  uint v = *reinterpret_cast<const uint*>(xlb + (size_t)((uint)s * (uint)(DIM * 2)) + laneB);
  acc[0] = fmaf(p, __uint_as_float(v << 16), acc[0]);
  acc[1] = fmaf(p, __uint_as_float(v & 0xffff0000u), acc[1]);
}

// ---------------- per-node wave gather: softmax + aggregate + bias + LN + ReLU ----------------
// One WAVE per node (4 waves/block, independent). src+p cached in LDS; no global re-reads in j-loop.
template<int H, int DIM, bool BF16_OUT>
__global__ __launch_bounds__(256) void k_aggw(
    const ushort* __restrict__ xl,
    const float* __restrict__ al, const float* __restrict__ ar,
    const int* __restrict__ row_ptr, const int* __restrict__ csr_src,
    const float* __restrict__ bias, const float* __restrict__ gamma, const float* __restrict__ beta,
    float* __restrict__ out, int N)
{
  constexpr int EPL = DIM / 64;        // cols per lane: 4 (DIM=256) or 2 (DIM=128)
  constexpr int PST = 68;              // padded p stride: banks j, j+4, j+8, j+12 -> conflict-free
  const int tid = (int)threadIdx.x;
  const int wid = tid >> 6, lane = tid & 63;
  __shared__ float plds_all[4][H * PST];
  __shared__ int   slds_all[4][64];
  float* plds = plds_all[wid];
  int*   slds = slds_all[wid];
  const int n = blockIdx.x * 4 + wid;
  if (n >= N) return;
  const int start = __builtin_amdgcn_readfirstlane(row_ptr[n]);
  const int end   = __builtin_amdgcn_readfirstlane(row_ptr[n + 1]);
  const int deg   = end - start;
  const int hm    = (H == 4) ? (lane >> 4) : 0;
  const int hb    = hm * PST;
  const int laneB = lane * (EPL * 2);

  float arv[H];
  #pragma unroll
  for (int h = 0; h < H; h++) arv[h] = ar[(size_t)n * H + h];

  float acc[EPL];
  #pragma unroll
  for (int e = 0; e < EPL; e++) acc[e] = 0.f;
  float psum[H];
  const char* xlb = (const char*)xl;

  auto gather = [&](int cnt){
    int j = 0;
    for (; j + 8 <= cnt; j += 8){
      int s0 = slds[j+0], s1 = slds[j+1], s2 = slds[j+2], s3 = slds[j+3];
      int s4 = slds[j+4], s5 = slds[j+5], s6 = slds[j+6], s7 = slds[j+7];
      float q0 = plds[hb+j+0], q1 = plds[hb+j+1], q2 = plds[hb+j+2], q3 = plds[hb+j+3];
      float q4 = plds[hb+j+4], q5 = plds[hb+j+5], q6 = plds[hb+j+6], q7 = plds[hb+j+7];
      if constexpr (EPL == 4){
        gstep4<DIM>(xlb, laneB, s0, q0, acc); gstep4<DIM>(xlb, laneB, s1, q1, acc);
        gstep4<DIM>(xlb, laneB, s2, q2, acc); gstep4<DIM>(xlb, laneB, s3, q3, acc);
        gstep4<DIM>(xlb, laneB, s4, q4, acc); gstep4<DIM>(xlb, laneB, s5, q5, acc);
        gstep4<DIM>(xlb, laneB, s6, q6, acc); gstep4<DIM>(xlb, laneB, s7, q7, acc);
      } else {
        gstep2<DIM>(xlb, laneB, s0, q0, acc); gstep2<DIM>(xlb, laneB, s1, q1, acc);
        gstep2<DIM>(xlb, laneB, s2, q2, acc); gstep2<DIM>(xlb, laneB, s3, q3, acc);
        gstep2<DIM>(xlb, laneB, s4, q4, acc); gstep2<DIM>(xlb, laneB, s5, q5, acc);
        gstep2<DIM>(xlb, laneB, s6, q6, acc); gstep2<DIM>(xlb, laneB, s7, q7, acc);
      }
    }
    for (; j + 2 <= cnt; j += 2){
      int s0 = slds[j+0], s1 = slds[j+1];
      float q0 = plds[hb+j+0], q1 = plds[hb+j+1];
      if constexpr (EPL == 4){ gstep4<DIM>(xlb, laneB, s0, q0, acc); gstep4<DIM>(xlb, laneB, s1, q1, acc); }
      else                   { gstep2<DIM>(xlb, laneB, s0, q0, acc); gstep2<DIM>(xlb, laneB, s1, q1, acc); }
    }
    if (j < cnt){
      int s0 = slds[j];
      float q0 = plds[hb+j];
      if constexpr (EPL == 4) gstep4<DIM>(xlb, laneB, s0, q0, acc);
      else                    gstep2<DIM>(xlb, laneB, s0, q0, acc);
    }
  };

  if (deg <= 64){
    // ---- fast path: one al gather; e/p in registers; src cached to LDS ----
    int src = csr_src[start + (lane < deg ? lane : deg - 1)];
    slds[lane] = src;
    float e[H];
    if constexpr (H == 4){
      float4 a4 = *reinterpret_cast<const float4*>(&al[(size_t)src * 4]);
      e[0] = a4.x + arv[0]; e[1] = a4.y + arv[1]; e[2] = a4.z + arv[2]; e[3] = a4.w + arv[3];
    } else {
      e[0] = al[src] + arv[0];
    }
    #pragma unroll
    for (int h = 0; h < H; h++){
      e[h] = e[h] > 0.f ? e[h] : 0.2f * e[h];
      if (lane >= deg) e[h] = -1e30f;
    }
    float mx[H];
    #pragma unroll
    for (int h = 0; h < H; h++){
      mx[h] = e[h];
      #pragma unroll
      for (int off = 32; off; off >>= 1) mx[h] = fmaxf(mx[h], __shfl_xor(mx[h], off));
    }
    #pragma unroll
    for (int h = 0; h < H; h++){
      float p = (lane < deg) ? __expf(e[h] - mx[h]) : 0.f;
      plds[h * PST + lane] = p;
      psum[h] = p;
      #pragma unroll
      for (int off = 32; off; off >>= 1) psum[h] += __shfl_xor(psum[h], off);
    }
    __asm__ volatile("s_waitcnt lgkmcnt(0)" ::: "memory");
    __builtin_amdgcn_wave_barrier();
    gather(deg);
  } else {
    // ---- slow path (deg > 64, rare): global max pass then chunked ----
    float mx[H];
    #pragma unroll
    for (int h = 0; h < H; h++) mx[h] = -1e30f;
    for (int i = start + lane; i < end; i += 64){
      int src = csr_src[i];
      if constexpr (H == 4){
        float4 a4 = *reinterpret_cast<const float4*>(&al[(size_t)src * 4]);
        float e0 = a4.x + arv[0]; e0 = e0 > 0.f ? e0 : 0.2f * e0; mx[0] = fmaxf(mx[0], e0);
        float e1 = a4.y + arv[1]; e1 = e1 > 0.f ? e1 : 0.2f * e1; mx[1] = fmaxf(mx[1], e1);
        float e2 = a4.z + arv[2]; e2 = e2 > 0.f ? e2 : 0.2f * e2; mx[2] = fmaxf(mx[2], e2);
        float e3 = a4.w + arv[3]; e3 = e3 > 0.f ? e3 : 0.2f * e3; mx[3] = fmaxf(mx[3], e3);
      } else {
        float e = al[src] + arv[0]; e = e > 0.f ? e : 0.2f * e; mx[0] = fmaxf(mx[0], e);
      }
    }
    #pragma unroll
    for (int h = 0; h < H; h++){
      #pragma unroll
      for (int off = 32; off; off >>= 1) mx[h] = fmaxf(mx[h], __shfl_xor(mx[h], off));
    }
    #pragma unroll
    for (int h = 0; h < H; h++) psum[h] = 0.f;
    for (int c0 = start; c0 < end; c0 += 64){
      const int cnt = min(64, end - c0);
      __asm__ volatile("s_waitcnt lgkmcnt(0)" ::: "memory");   // prev chunk consumed
      __builtin_amdgcn_wave_barrier();
      if (lane < cnt){
        int src = csr_src[c0 + lane];
        slds[lane] = src;
        if constexpr (H == 4){
          float4 a4 = *reinterpret_cast<const float4*>(&al[(size_t)src * 4]);
          float e0 = a4.x + arv[0]; e0 = e0 > 0.f ? e0 : 0.2f * e0; float p0 = __expf(e0 - mx[0]);
          float e1 = a4.y + arv[1]; e1 = e1 > 0.f ? e1 : 0.2f * e1; float p1 = __expf(e1 - mx[1]);
          float e2 = a4.z + arv[2]; e2 = e2 > 0.f ? e2 : 0.2f * e2; float p2 = __expf(e2 - mx[2]);
          float e3 = a4.w + arv[3]; e3 = e3 > 0.f ? e3 : 0.2f * e3; float p3 = __expf(e3 - mx[3]);
          plds[0 * PST + lane] = p0; plds[1 * PST + lane] = p1;
          plds[2 * PST + lane] = p2; plds[3 * PST + lane] = p3;
          psum[0] += p0; psum[1] += p1; psum[2] += p2; psum[3] += p3;
        } else {
          float e = al[src] + arv[0]; e = e > 0.f ? e : 0.2f * e; float p = __expf(e - mx[0]);
          plds[lane] = p; psum[0] += p;
        }
      }
      __asm__ volatile("s_waitcnt lgkmcnt(0)" ::: "memory");
      __builtin_amdgcn_wave_barrier();
      gather(cnt);
    }
    #pragma unroll
    for (int h = 0; h < H; h++){
      #pragma unroll
      for (int off = 32; off; off >>= 1) psum[h] += __shfl_xor(psum[h], off);
    }
  }

  // ---- normalize ----
  float ssel;
  if constexpr (H == 4){
    ssel = (hm == 0) ? psum[0] : (hm == 1) ? psum[1] : (hm == 2) ? psum[2] : psum[3];
  } else {
    ssel = psum[0];
  }
  const float inv = 1.f / (ssel + 1e-16f);

  // ---- bias + LayerNorm + ReLU (all-shuffle, no LDS) ----
  float v[EPL];
  if constexpr (EPL == 4){
    float4 bb = *reinterpret_cast<const float4*>(&bias[lane * 4]);
    v[0] = fmaf(acc[0], inv, bb.x); v[1] = fmaf(acc[1], inv, bb.y);
    v[2] = fmaf(acc[2], inv, bb.z); v[3] = fmaf(acc[3], inv, bb.w);
  } else {
    float2 bb = *reinterpret_cast<const float2*>(&bias[lane * 2]);
    v[0] = fmaf(acc[0], inv, bb.x); v[1] = fmaf(acc[1], inv, bb.y);
  }
  float s1 = 0.f, s2 = 0.f;
  #pragma unroll
  for (int e = 0; e < EPL; e++){ s1 += v[e]; s2 += v[e] * v[e]; }
  #pragma unroll
  for (int off = 32; off; off >>= 1){ s1 += __shfl_xor(s1, off); s2 += __shfl_xor(s2, off); }
  const float mu = s1 / DIM;
  const float rstd = rsqrtf(s2 / DIM - mu * mu + EPS_LN);

  if constexpr (EPL == 4){
    float4 gg = *reinterpret_cast<const float4*>(&gamma[lane * 4]);
    float4 be = *reinterpret_cast<const float4*>(&beta[lane * 4]);
    float o0 = fmaxf((v[0] - mu) * rstd * gg.x + be.x, 0.f);
    float o1 = fmaxf((v[1] - mu) * rstd * gg.y + be.y, 0.f);
    float o2 = fmaxf((v[2] - mu) * rstd * gg.z + be.z, 0.f);
    float o3 = fmaxf((v[3] - mu) * rstd * gg.w + be.w, 0.f);
    if constexpr (BF16_OUT){
      uint2 pk;
      pk.x = (uint)f2bf(o0) | ((uint)f2bf(o1) << 16);
      pk.y = (uint)f2bf(o2) | ((uint)f2bf(o3) << 16);
      *reinterpret_cast<uint2*>(&reinterpret_cast<ushort*>(out)[(size_t)n * DIM + lane * 4]) = pk;
    } else {
      *reinterpret_cast<float4*>(&out[(size_t)n * DIM + lane * 4]) = make_float4(o0, o1, o2, o3);
    }
  } else {
    float2 gg = *reinterpret_cast<const float2*>(&gamma[lane * 2]);
    float2 be = *reinterpret_cast<const float2*>(&beta[lane * 2]);
    float o0 = fmaxf((v[0] - mu) * rstd * gg.x + be.x, 0.f);
    float o1 = fmaxf((v[1] - mu) * rstd * gg.y + be.y, 0.f);
    if constexpr (BF16_OUT){
      uint pk = (uint)f2bf(o0) | ((uint)f2bf(o1) << 16);
      reinterpret_cast<uint*>(out)[(size_t)n * (DIM / 2) + lane] = pk;
    } else {
      *reinterpret_cast<float2*>(&out[(size_t)n * DIM + lane * 2]) = make_float2(o0, o1);
    }
  }
}

// ---------------- pooling over pos ranges ----------------
__global__ __launch_bounds__(128) void k_pool(const float* __restrict__ h, const int* __restrict__ pos,
    float* __restrict__ pool_sum, unsigned* __restrict__ pool_max){
  const int c = (int)threadIdx.x;           // channel 0..127
  const int g = blockIdx.x >> 2;            // graph
  const int q = blockIdx.x & 3;             // quarter
  const int s = pos[g], e = pos[g + 1];
  const int len = e - s;
  if (len <= 0) return;
  const int chunk = (len + 3) >> 2;
  const int n0 = s + q * chunk;
  const int n1 = min(n0 + chunk, e);
  if (n0 >= n1) return;
  float sum = 0.f, mx = 0.f;                // post-ReLU values >= 0
  for (int n = n0; n < n1; n++){
    float v = h[(size_t)n * 128 + c];
    sum += v; mx = fmaxf(mx, v);
  }
  atomicAdd(&pool_sum[g * 128 + c], sum);
  atomicMax(&pool_max[g * 128 + c], __float_as_uint(mx));
}

__global__ __launch_bounds__(128) void k_final(const float* __restrict__ pool_sum,
    const unsigned* __restrict__ pool_max, const int* __restrict__ pos,
    const float* __restrict__ Wp, const float* __restrict__ bp, float* __restrict__ out){
  const int g = blockIdx.x;
  const int j = (int)threadIdx.x;
  float inv = 1.f / fmaxf((float)(pos[g + 1] - pos[g]), 1.f);
  float acc = bp[j];
  #pragma unroll 4
  for (int k = 0; k < 128; k++)
    acc = fmaf(pool_sum[g * 128 + k] * inv, Wp[k * 128 + j], acc);
  #pragma unroll 4
  for (int k = 0; k < 128; k++)
    acc = fmaf(__uint_as_float(pool_max[g * 128 + k]), Wp[(128 + k) * 128 + j], acc);
  out[g * 128 + j] = acc;
}

// ---------------- launch ----------------
extern "C" void kernel_launch(void* const* d_in, const int* in_sizes, int n_in,
                              void* d_out, int out_size, void* d_ws, size_t ws_size,
                              hipStream_t stream){
  const float* x     = (const float*)d_in[0];
  const int*   ei    = (const int*)d_in[1];
  const int*   batch = (const int*)d_in[2];
  const float* W1    = (const float*)d_in[3];
  const float* asrc1 = (const float*)d_in[4];
  const float* adst1 = (const float*)d_in[5];
  const float* b1    = (const float*)d_in[6];
  const float* g1    = (const float*)d_in[7];
  const float* be1   = (const float*)d_in[8];
  const float* W2    = (const float*)d_in[9];
  const float* asrc2 = (const float*)d_in[10];
  const float* adst2 = (const float*)d_in[11];
  const float* b2    = (const float*)d_in[12];
  const float* g2    = (const float*)d_in[13];
  const float* be2   = (const float*)d_in[14];
  const float* W3    = (const float*)d_in[15];
  const float* asrc3 = (const float*)d_in[16];
  const float* adst3 = (const float*)d_in[17];
  const float* b3    = (const float*)d_in[18];
  const float* g3    = (const float*)d_in[19];
  const float* be3   = (const float*)d_in[20];
  const float* Wp    = (const float*)d_in[21];
  const float* bp    = (const float*)d_in[22];

  const int N = in_sizes[0] / 128;
  const int E = in_sizes[1] / 2;
  const int G = out_size / 128;
  const int EN = E + N;

  char* ws = (char*)d_ws;
  size_t off = 0;
  auto alloc = [&](size_t bytes) -> char* {
    char* p = ws + off;
    off = (off + bytes + 255) & ~(size_t)255;
    return p;
  };
  // region0: x_bf (N*128 bf16) lives here until aggw-L1 overwrites it with h_bf (N*256 bf16)
  ushort*   region0  = (ushort*)alloc((size_t)N * 256 * 2);
  ushort*   x_bf     = region0;
  ushort*   h_bf     = region0;
  ushort*   xbufA    = (ushort*)alloc((size_t)N * 256 * 2);  // xl (bf16)
  float*    xbufB    = (float*)alloc((size_t)N * 128 * 4);   // layer-3 output (f32, for pooling)
  float*    al       = (float*)alloc((size_t)N * 4 * 4);
  float*    ar       = (float*)alloc((size_t)N * 4 * 4);
  int*      deg      = (int*)alloc((size_t)N * 4);
  int*      row_ptr  = (int*)alloc((size_t)(N + 1) * 4);
  int*      cursor   = (int*)alloc((size_t)N * 4);
  int*      csr_src  = (int*)alloc((size_t)EN * 4);
  int*      pos      = (int*)alloc((size_t)(G + 1) * 4);
  float*    pool_sum = (float*)alloc((size_t)G * 128 * 4);
  unsigned* pool_max = (unsigned*)alloc((size_t)G * 128 * 4);
  ushort*   W1t      = (ushort*)alloc((size_t)256 * 128 * 2);  // [N=256][K=128]
  ushort*   W2t      = (ushort*)alloc((size_t)256 * 256 * 2);  // [256][256]
  ushort*   W3t      = (ushort*)alloc((size_t)128 * 256 * 2);  // [128][256]
  const int NB = (N + 1023) / 1024;
  int*      bsum     = (int*)alloc((size_t)NB * 4);

  hipMemsetAsync(deg, 0, (size_t)N * 4, stream);
  hipMemsetAsync(pool_sum, 0, (size_t)G * 128 * 4, stream);
  hipMemsetAsync(pool_max, 0, (size_t)G * 128 * 4, stream);

  // CSR build + graph bounds + dtype prep
  k_deg<<<(EN + 255) / 256, 256, 0, stream>>>(ei, deg, E, N);
  k_bsum<<<NB, 1024, 0, stream>>>(deg, bsum, N);
  k_misc<<<2, 256, 0, stream>>>(bsum, NB, batch, pos, N, G);
  k_scan2<<<NB, 1024, 0, stream>>>(deg, bsum, row_ptr, cursor, N);
  k_scatter<<<(EN + 255) / 256, 256, 0, stream>>>(ei, cursor, csr_src, E, N);
  {
    int total = N * 32 + 256 * 128 + 256 * 256 + 128 * 256;
    k_prep<<<(total + 255) / 256, 256, 0, stream>>>(x, x_bf, W1, W1t, W2, W2t, W3, W3t, N);
  }

  const int MB = (N + 127) / 128;
  const int NB4 = (N + 3) / 4;

  // Layer 1: 128 -> 256, H=4, C=64
  k_mm<128, 256, 4><<<dim3(MB, 2), 256, 0, stream>>>(x_bf, W1t, xbufA, asrc1, adst1, al, ar, N);
  k_aggw<4, 256, true><<<NB4, 256, 0, stream>>>(xbufA, al, ar, row_ptr, csr_src, b1, g1, be1, (float*)h_bf, N);

  // Layer 2: 256 -> 256, H=4, C=64
  k_mm<256, 256, 4><<<dim3(MB, 2), 256, 0, stream>>>(h_bf, W2t, xbufA, asrc2, adst2, al, ar, N);
  k_aggw<4, 256, true><<<NB4, 256, 0, stream>>>(xbufA, al, ar, row_ptr, csr_src, b2, g2, be2, (float*)h_bf, N);

  // Layer 3: 256 -> 128, H=1, C=128
  k_mm<256, 128, 1><<<dim3(MB, 1), 256, 0, stream>>>(h_bf, W3t, xbufA, asrc3, adst3, al, ar, N);
  k_aggw<1, 128, false><<<NB4, 256, 0, stream>>>(xbufA, al, ar, row_ptr, csr_src, b3, g3, be3, xbufB, N);

  // Pooling + final projection
  k_pool<<<G * 4, 128, 0, stream>>>(xbufB, pos, pool_sum, pool_max);
  k_final<<<G, 128, 0, stream>>>(pool_sum, pool_max, pos, Wp, bp, (float*)d_out);
}